// Round 10
// baseline (220.170 us; speedup 1.0000x reference)
//
#include <hip/hip_runtime.h>
#include <stdint.h>

#define C      1024
#define NH     16
#define HS     64
#define CT     65536
#define PAST   61440   // CT - WINDOW
#define KEEP   12288   // MIN_KV - WINDOW
#define NCOMP  192     // KEEP/64
#define NSEL   32
#define NB     8192    // selection bins
#define NBLK   256     // mega-kernel grid (co-resident: 256 blocks, 2048 thr-slots/CU)

typedef unsigned long long ull;

// monotone transform: larger float => smaller u (asc u == desc value)
__device__ __forceinline__ unsigned int desc_key(float f) {
    unsigned int b = __float_as_uint(f);
    return (b >> 31) ? b : (~b & 0x7FFFFFFFu);
}
__device__ __forceinline__ float u_to_f(unsigned int u) {
    unsigned int b = (u & 0x80000000u) ? u : (0x7FFFFFFFu - u);
    return __uint_as_float(b);
}
// monotone linear bin: s descending <-> bin ascending
__device__ __forceinline__ int bin_of(float s, float hi, float scale) {
    int b = (int)((hi - s) * scale);
    return b < 0 ? 0 : (b > NB - 1 ? NB - 1 : b);
}
__device__ __forceinline__ void load_params(const unsigned* umin, const unsigned* umax,
                                            int h, float* hi, float* sc) {
    float h2 = u_to_f(umin[h]);
    float lo = u_to_f(umax[h]);
    float r = h2 - lo;
    *hi = h2;
    *sc = (r > 0.f) ? (float)(NB - 1) / r : 0.f;
}

// device-wide barrier: arrival = device atomicAdd; wait = relaxed agent-scope
// LOAD (no RMW line bouncing) + s_sleep backoff. One poller per block.
__device__ __forceinline__ void gsync(unsigned* cnt) {
    __syncthreads();
    if (threadIdx.x == 0) {
        __threadfence();                       // release this block's writes
        atomicAdd(cnt, 1u);
        while (__hip_atomic_load(cnt, __ATOMIC_RELAXED, __HIP_MEMORY_SCOPE_AGENT) < NBLK)
            __builtin_amdgcn_s_sleep(32);      // ~2K cycles between polls
        __threadfence();                       // acquire: invalidate stale lines
    }
    __syncthreads();
}

// ---------------- K1: q/k/v projections + all zero-inits ---------------------
__global__ void k_proj(const float* __restrict__ x, const float* __restrict__ Wr,
                       const float* __restrict__ Wk, const float* __restrict__ Wv,
                       float* __restrict__ q, float* __restrict__ kn, float* __restrict__ vn,
                       unsigned* __restrict__ hist, unsigned* __restrict__ umin,
                       unsigned* __restrict__ umax, ull* __restrict__ cs_fix,
                       unsigned* __restrict__ bar) {
    int id = blockIdx.x * 256 + threadIdx.x;
    if (id < NH * NB) hist[id] = 0;
    if (blockIdx.x == 699 && threadIdx.x < 8) bar[threadIdx.x] = 0u;
    if (blockIdx.x == 700) {
        if (threadIdx.x < 16) umin[threadIdx.x] = 0xFFFFFFFFu;
        else if (threadIdx.x < 32) umax[threadIdx.x - 16] = 0u;
    }
    if (blockIdx.x == 701 && threadIdx.x < 256) cs_fix[threadIdx.x] = 0ull;

    int w = blockIdx.x * (blockDim.x >> 6) + (threadIdx.x >> 6); // 0..3071
    int lane = threadIdx.x & 63;
    int mat = w >> 10, row = w & 1023;
    const float* W = (mat == 0) ? Wr : (mat == 1) ? Wk : Wv;
    const float4* Wrow = (const float4*)(W + (size_t)row * C);
    const float4* x4 = (const float4*)x;
    float acc = 0.f;
#pragma unroll
    for (int i = 0; i < 4; ++i) {
        float4 a = Wrow[i * 64 + lane];
        float4 b = x4[i * 64 + lane];
        acc += a.x * b.x + a.y * b.y + a.z * b.z + a.w * b.w;
    }
#pragma unroll
    for (int off = 32; off; off >>= 1) acc += __shfl_xor(acc, off);
    if (lane == 0) { (mat == 0 ? q : (mat == 1 ? kn : vn))[row] = acc; }
}

// ------- K2: scores s[h][t] = qh.k_cache[t,h]; 16 tokens/wave, 64B writes ----
__global__ void k_scores(const float* __restrict__ kc, const float* __restrict__ q,
                         float* __restrict__ s, unsigned* __restrict__ umin,
                         unsigned* __restrict__ umax) {
    __shared__ float sc_l[4][16][17];
    __shared__ float smn[4][16], smx[4][16];
    int wave = threadIdx.x >> 6, lane = threadIdx.x & 63;
    int wid = blockIdx.x * 4 + wave;           // 0..4095
    int t0 = wid * 16;
    const float4* q4 = (const float4*)q;
    float4 qv[4];
#pragma unroll
    for (int i = 0; i < 4; ++i) qv[i] = q4[i * 64 + lane];
    float mnv[4] = {3.4e38f, 3.4e38f, 3.4e38f, 3.4e38f};
    float mxv[4] = {-3.4e38f, -3.4e38f, -3.4e38f, -3.4e38f};
    for (int tt = 0; tt < 16; ++tt) {
        const float4* row = (const float4*)(kc + (size_t)(t0 + tt) * C);
        float acc[4];
#pragma unroll
        for (int i = 0; i < 4; ++i) {
            float4 a = row[i * 64 + lane];
            acc[i] = a.x * qv[i].x + a.y * qv[i].y + a.z * qv[i].z + a.w * qv[i].w;
        }
#pragma unroll
        for (int off = 8; off; off >>= 1) {
#pragma unroll
            for (int i = 0; i < 4; ++i) acc[i] += __shfl_xor(acc[i], off);
        }
        if ((lane & 15) == 0) {
            int g = lane >> 4;
#pragma unroll
            for (int i = 0; i < 4; ++i) {
                sc_l[wave][4 * i + g][tt] = acc[i];
                mnv[i] = fminf(mnv[i], acc[i]);
                mxv[i] = fmaxf(mxv[i], acc[i]);
            }
        }
    }
    __syncthreads();
    // contiguous 64B-per-head writes (16 consecutive tokens per 16-lane group)
    int tt2 = lane & 15;
#pragma unroll
    for (int r = 0; r < 4; ++r) {
        int h = r * 4 + (lane >> 4);
        s[(size_t)h * CT + t0 + tt2] = sc_l[wave][h][tt2];
    }
    if (blockIdx.x < 960) {                     // all 4 waves fully in PAST region
        if ((lane & 15) == 0) {
            int g = lane >> 4;
#pragma unroll
            for (int i = 0; i < 4; ++i) { smn[wave][4 * i + g] = mnv[i]; smx[wave][4 * i + g] = mxv[i]; }
        }
        __syncthreads();
        if (threadIdx.x < 16) {
            int h = threadIdx.x;
            float mn = smn[0][h], mx = smx[0][h];
            for (int w2 = 1; w2 < 4; ++w2) {
                mn = fminf(mn, smn[w2][h]);
                mx = fmaxf(mx, smx[w2][h]);
            }
            atomicMin(&umin[h], desc_key(mx));
            atomicMax(&umax[h], desc_key(mn));
        }
    }
}

// -------- K3 (mega): hist -> scan||winsum -> scatter -> rank -> attn -> out --
__global__ __launch_bounds__(1024, 2) void k_mega(
        const float* __restrict__ s, const float* __restrict__ vc,
        const unsigned* __restrict__ umin, const unsigned* __restrict__ umax,
        unsigned* __restrict__ base, unsigned* __restrict__ Tarr,
        ull* __restrict__ G, unsigned short* __restrict__ stok,
        ull* __restrict__ cs_fix, float* __restrict__ part,
        const float* __restrict__ q, const float* __restrict__ kn,
        const float* __restrict__ vn, const float* __restrict__ Wo,
        float* __restrict__ out, unsigned* __restrict__ bar) {
    const int bid = blockIdx.x, tid = threadIdx.x;
    const int lane = tid & 63, wave = tid >> 6;
    __shared__ __align__(16) char smem[40960];

    // ---- Phase C: histogram (16 blocks per head, LDS hist -> global atomics)
    {
        unsigned* lh = (unsigned*)smem;
        int h = bid >> 4, seg = bid & 15;
        for (int i = tid; i < NB; i += 1024) lh[i] = 0;
        __syncthreads();
        float hi, sc; load_params(umin, umax, h, &hi, &sc);
        const float* sh = s + (size_t)h * CT + seg * 3840;
        for (int i = tid; i < 3840; i += 1024)
            atomicAdd(&lh[bin_of(sh[i], hi, sc)], 1u);
        __syncthreads();
        unsigned* gh = base + h * NB;
        for (int i = tid; i < NB; i += 1024) {
            unsigned c = lh[i];
            if (c) atomicAdd(&gh[i], c);
        }
    }
    gsync(bar + 0);

    // ---- Phase D: scan+threshold (blocks 0..15) || window-chunk sums (rest)
    if (bid < 16) {
        unsigned* wsum = (unsigned*)smem;
        int h = bid;
        unsigned* B = base + h * NB;
        unsigned cnt[8];
        unsigned loc = 0;
        int b0 = tid * 8;
#pragma unroll
        for (int k = 0; k < 8; ++k) { cnt[k] = B[b0 + k]; loc += cnt[k]; }
        unsigned run = loc;
#pragma unroll
        for (int off = 1; off < 64; off <<= 1) {
            unsigned n = __shfl_up(run, off);
            if (lane >= off) run += n;
        }
        if (lane == 63) wsum[wave] = run;
        __syncthreads();
        if (wave == 0 && lane < 16) {
            unsigned v = wsum[lane];
#pragma unroll
            for (int off = 1; off < 16; off <<= 1) {
                unsigned n = __shfl_up(v, off);
                if (lane >= off) v += n;
            }
            wsum[lane] = v;
        }
        __syncthreads();
        unsigned r = run - loc + (wave ? wsum[wave - 1] : 0u);
#pragma unroll
        for (int k = 0; k < 8; ++k) {
            unsigned c = cnt[k];
            B[b0 + k] = r;
            unsigned inc = r + c;
            if (r < KEEP && inc >= KEEP) Tarr[h] = (unsigned)(b0 + k);
            r = inc;
        }
    } else {
        int gw = (bid - 16) * 16 + wave;        // 0..3839
        if (gw < NH * 64) {
            int h = gw >> 6, c2 = gw & 63;
            float v = s[(size_t)h * CT + PAST + c2 * 64 + lane];
            long long f = llrintf(v * 16777216.f);
#pragma unroll
            for (int off = 32; off; off >>= 1) f += __shfl_xor(f, off);
            if (lane == 0) atomicAdd(&cs_fix[NCOMP + c2], (ull)f);
        }
    }
    gsync(bar + 1);

    // ---- Phase E: scatter candidates (bins <= T)
    for (int i = bid * 1024 + tid; i < NH * PAST; i += NBLK * 1024) {
        int h = i / PAST, t = i - h * PAST;
        float hi, sc; load_params(umin, umax, h, &hi, &sc);
        float v = s[(size_t)h * CT + t];
        int b = bin_of(v, hi, sc);
        if ((unsigned)b <= Tarr[h]) {
            unsigned pos = atomicAdd(&base[h * NB + b], 1u);
            G[(size_t)h * 65536 + pos] = ((ull)desc_key(v) << 16) | (unsigned)t;
        }
    }
    gsync(bar + 2);

    // ---- Phase F: exact rank within bin; emit stok + compacted chunk sums
    {
        ull* csl = (ull*)smem;
        if (tid < NCOMP) csl[tid] = 0ull;
        __syncthreads();
        int h = bid >> 4, seg = bid & 15;
        float hi, sc; load_params(umin, umax, h, &hi, &sc);
        unsigned T = Tarr[h];
        unsigned ncand = base[h * NB + T];
        const ull* Gh = G + (size_t)h * 65536;
        for (unsigned p = seg * 1024 + tid; p < ncand; p += 16384) {
            ull pk = Gh[p];
            unsigned u = (unsigned)(pk >> 16);
            float v = u_to_f(u);
            int b = bin_of(v, hi, sc);
            unsigned start = b ? base[h * NB + b - 1] : 0u;
            unsigned end = base[h * NB + b];
            unsigned rank = start;
            for (unsigned j = start; j < end; ++j) rank += (Gh[j] < pk) ? 1u : 0u;
            if (rank < KEEP) {
                stok[h * KEEP + rank] = (unsigned short)(pk & 0xFFFFull);
                long long f = llrintf(v * 16777216.f);
                atomicAdd(&csl[rank >> 6], (ull)f);
            }
        }
        __syncthreads();
        if (tid < NCOMP) {
            ull c = csl[tid];
            if (c) atomicAdd(&cs_fix[tid], c);
        }
    }
    gsync(bar + 3);

    // ---- Phase H: top-32 (redundant per block) + partial softmax+PV (2 pairs)
    {
        ull* key = (ull*)smem;                       // 2048 B
        unsigned* sel_l = (unsigned*)(smem + 2048);  // 128 B
        float* scm = (float*)(smem + 2176);          // 512 B (2x64)
        float* exb = (float*)(smem + 2688);          // 512 B (2x64)
        float* vbuf = (float*)(smem + 3200);         // 2 x 64 x 68 floats
        if (tid < 256) {
            long long v = (long long)cs_fix[tid];
            ull bb = (ull)(v + (1ll << 45));
            key[tid] = (((1ull << 46) - bb) << 8) | (unsigned)tid;
        }
        __syncthreads();
        for (unsigned k = 2; k <= 256; k <<= 1) {
            for (unsigned j = k >> 1; j > 0; j >>= 1) {
                if (tid < 256) {
                    unsigned ixj = tid ^ j;
                    if (ixj > (unsigned)tid) {
                        ull a = key[tid], b = key[ixj];
                        bool up = ((tid & k) == 0);
                        if (up ? (a > b) : (a < b)) { key[tid] = b; key[ixj] = a; }
                    }
                }
                __syncthreads();
            }
        }
        if (tid < NSEL) sel_l[tid] = (unsigned)(key[tid] & 0xFFull);
        __syncthreads();

        int su = tid >> 9, sid = tid & 511;
        int p = bid * 2 + su;                    // 0..511
        int h = p >> 5, ci = p & 31;
        int c = (int)sel_l[ci];
        int g = sid >> 3, q8 = sid & 7;
        int t = (c < NCOMP) ? (int)stok[h * KEEP + c * 64 + g]
                            : (PAST + (c - NCOMP) * 64 + g);
        if (q8 == 0) scm[su * 64 + g] = s[(size_t)h * CT + t] * 0.125f;
        __syncthreads();
        float m = -1e30f;
        for (int j = 0; j < 64; ++j) m = fmaxf(m, scm[su * 64 + j]);
        float e = expf(scm[su * 64 + g] - m);
        if (q8 == 0) exb[su * 64 + g] = e;
        const float4* vrow = (const float4*)(vc + (size_t)t * C + h * HS);
        float4 v0 = vrow[q8 * 2], v1 = vrow[q8 * 2 + 1];
        float* vb = vbuf + su * 4352 + g * 68 + q8 * 8;
        vb[0] = e * v0.x; vb[1] = e * v0.y; vb[2] = e * v0.z; vb[3] = e * v0.w;
        vb[4] = e * v1.x; vb[5] = e * v1.y; vb[6] = e * v1.z; vb[7] = e * v1.w;
        __syncthreads();
        if (sid < 64) {
            float acc = 0.f;
            for (int g2 = 0; g2 < 64; ++g2) acc += vbuf[su * 4352 + g2 * 68 + sid];
            float* P = part + (size_t)(h * 32 + ci) * 68;
            P[2 + sid] = acc;
            if (sid == 0) {
                float es = 0.f;
                for (int g2 = 0; g2 < 64; ++g2) es += exb[su * 64 + g2];
                P[0] = m;
                P[1] = es;
            }
        }
    }
    gsync(bar + 4);
    if (bid >= 64) return;

    // ---- Phase J: combine partials -> y (LDS, redundant) -> out = y @ Wo.T
    {
        float* yl = (float*)smem;                 // 4 KB
        float* qdl = (float*)(smem + 4096);       // 64 B
        if (tid < 16) {
            float qd = 0.f;
            for (int l = 0; l < 64; ++l) qd += q[tid * 64 + l] * kn[tid * 64 + l];
            qdl[tid] = qd;
        }
        __syncthreads();
        {
            int h = tid >> 6, ln = tid & 63;
            float a_new = qdl[h] * 0.125f;
            const float* P0 = part + (size_t)h * 32 * 68;
            float m = a_new;
            for (int ci = 0; ci < 32; ++ci) m = fmaxf(m, P0[ci * 68]);
            float den = expf(a_new - m);
            float acc = den * vn[h * HS + ln];
            for (int ci = 0; ci < 32; ++ci) {
                float w = expf(P0[ci * 68] - m);
                den += w * P0[ci * 68 + 1];
                acc += w * P0[ci * 68 + 2 + ln];
            }
            yl[tid] = acc / den;
        }
        __syncthreads();
        int r = bid * 16 + wave;                  // 0..1023
        const float4* Wrow = (const float4*)(Wo + (size_t)r * C);
        const float4* y4 = (const float4*)yl;
        float acc = 0.f;
#pragma unroll
        for (int i = 0; i < 4; ++i) {
            float4 a = Wrow[i * 64 + lane];
            float4 b = y4[i * 64 + lane];
            acc += a.x * b.x + a.y * b.y + a.z * b.z + a.w * b.w;
        }
#pragma unroll
        for (int off = 32; off; off >>= 1) acc += __shfl_xor(acc, off);
        if (lane == 0) out[r] = acc;
    }
}

extern "C" void kernel_launch(void* const* d_in, const int* in_sizes, int n_in,
                              void* d_out, int out_size, void* d_ws, size_t ws_size,
                              hipStream_t stream) {
    const float* x  = (const float*)d_in[0];
    const float* kc = (const float*)d_in[1];
    const float* vc = (const float*)d_in[2];
    const float* Wr = (const float*)d_in[3];
    const float* Wk = (const float*)d_in[4];
    const float* Wv = (const float*)d_in[5];
    const float* Wo = (const float*)d_in[6];
    float* out = (float*)d_out;
    char* ws = (char*)d_ws;

    float* q    = (float*)(ws + 0);
    float* kn   = (float*)(ws + 8192);
    float* vn   = (float*)(ws + 16384);
    ull* cs_fix = (ull*)(ws + 32768);                         // 2 KiB
    float* part = (float*)(ws + 49152);                       // 139264 B
    unsigned short* stok = (unsigned short*)(ws + 196608);    // 393216 B
    unsigned* umin = (unsigned*)(ws + 602112);
    unsigned* umax = (unsigned*)(ws + 602176);
    unsigned* Tarr = (unsigned*)(ws + 602240);
    unsigned* bar  = (unsigned*)(ws + 602368);                // 8 barrier counters
    unsigned* base = (unsigned*)(ws + 655360);                // 512 KiB
    float* s = (float*)(ws + 2097152);                        // 4 MiB
    ull* G = (ull*)(ws + 6291456);                            // 8 MiB

    k_proj<<<768, 256, 0, stream>>>(x, Wr, Wk, Wv, q, kn, vn, base, umin, umax, cs_fix, bar);
    k_scores<<<1024, 256, 0, stream>>>(kc, q, s, umin, umax);
    k_mega<<<NBLK, 1024, 0, stream>>>(s, vc, umin, umax, base, Tarr, G, stok, cs_fix,
                                      part, q, kn, vn, Wo, out, bar);
}

// Round 11
// 143.414 us; speedup vs baseline: 1.5352x; 1.5352x over previous
//
#include <hip/hip_runtime.h>
#include <stdint.h>

#define C      1024
#define NH     16
#define HS     64
#define CT     65536
#define PAST   61440   // CT - WINDOW
#define KEEP   12288   // MIN_KV - WINDOW
#define NCOMP  192     // KEEP/64
#define NSEL   32
#define NB     8192    // selection bins
#define NBLK   256     // mega-kernel grid (1 block/CU, co-resident)

typedef unsigned long long ull;

// agent-scope relaxed accessors: write-through / fresh-read at coherence point
#define LD_A(p)   __hip_atomic_load((p), __ATOMIC_RELAXED, __HIP_MEMORY_SCOPE_AGENT)
#define ST_A(p,v) __hip_atomic_store((p), (v), __ATOMIC_RELAXED, __HIP_MEMORY_SCOPE_AGENT)

// monotone transform: larger float => smaller u (asc u == desc value)
__device__ __forceinline__ unsigned int desc_key(float f) {
    unsigned int b = __float_as_uint(f);
    return (b >> 31) ? b : (~b & 0x7FFFFFFFu);
}
__device__ __forceinline__ float u_to_f(unsigned int u) {
    unsigned int b = (u & 0x80000000u) ? u : (0x7FFFFFFFu - u);
    return __uint_as_float(b);
}
// monotone linear bin: s descending <-> bin ascending
__device__ __forceinline__ int bin_of(float s, float hi, float scale) {
    int b = (int)((hi - s) * scale);
    return b < 0 ? 0 : (b > NB - 1 ? NB - 1 : b);
}
__device__ __forceinline__ void load_params(const unsigned* umin, const unsigned* umax,
                                            int h, float* hi, float* sc) {
    float h2 = u_to_f(umin[h]);
    float lo = u_to_f(umax[h]);
    float r = h2 - lo;
    *hi = h2;
    *sc = (r > 0.f) ? (float)(NB - 1) / r : 0.f;
}

// fence-free device barrier: hierarchical relaxed arrival + relaxed poll.
// Preceding __syncthreads drains each wave's vmcnt (compiler-guaranteed), so
// all the block's write-through scoped stores are at the coherence point
// before tid0 arrives. No cache-wide fence ops anywhere.
#define GRPW 32        // uints between group counters (128B)
#define SITEW 288      // uints per barrier site
__device__ __forceinline__ void gsync(unsigned* bar, int site) {
    __syncthreads();
    if (threadIdx.x == 0) {
        asm volatile("s_waitcnt vmcnt(0)" ::: "memory");
        unsigned* g    = bar + site * SITEW + (blockIdx.x >> 5) * GRPW;
        unsigned* root = bar + site * SITEW + 8 * GRPW;
        if (__hip_atomic_fetch_add(g, 1u, __ATOMIC_RELAXED, __HIP_MEMORY_SCOPE_AGENT) == 31u)
            __hip_atomic_fetch_add(root, 1u, __ATOMIC_RELAXED, __HIP_MEMORY_SCOPE_AGENT);
        while (LD_A(root) < 8u) __builtin_amdgcn_s_sleep(16);
    }
    __syncthreads();
}

// ---------------- K1: q/k/v projections + all zero-inits ---------------------
__global__ void k_proj(const float* __restrict__ x, const float* __restrict__ Wr,
                       const float* __restrict__ Wk, const float* __restrict__ Wv,
                       float* __restrict__ q, float* __restrict__ kn, float* __restrict__ vn,
                       unsigned* __restrict__ hist, unsigned* __restrict__ umin,
                       unsigned* __restrict__ umax, ull* __restrict__ cs_fix,
                       unsigned* __restrict__ bar) {
    int id = blockIdx.x * 256 + threadIdx.x;
    if (id < NH * NB) hist[id] = 0;
    if (blockIdx.x >= 512 && blockIdx.x < 520)
        bar[(blockIdx.x - 512) * 256 + threadIdx.x] = 0u;
    if (blockIdx.x == 700) {
        if (threadIdx.x < 16) umin[threadIdx.x] = 0xFFFFFFFFu;
        else if (threadIdx.x < 32) umax[threadIdx.x - 16] = 0u;
    }
    if (blockIdx.x == 701 && threadIdx.x < 256) cs_fix[threadIdx.x] = 0ull;

    int w = blockIdx.x * (blockDim.x >> 6) + (threadIdx.x >> 6); // 0..3071
    int lane = threadIdx.x & 63;
    int mat = w >> 10, row = w & 1023;
    const float* W = (mat == 0) ? Wr : (mat == 1) ? Wk : Wv;
    const float4* Wrow = (const float4*)(W + (size_t)row * C);
    const float4* x4 = (const float4*)x;
    float acc = 0.f;
#pragma unroll
    for (int i = 0; i < 4; ++i) {
        float4 a = Wrow[i * 64 + lane];
        float4 b = x4[i * 64 + lane];
        acc += a.x * b.x + a.y * b.y + a.z * b.z + a.w * b.w;
    }
#pragma unroll
    for (int off = 32; off; off >>= 1) acc += __shfl_xor(acc, off);
    if (lane == 0) { (mat == 0 ? q : (mat == 1 ? kn : vn))[row] = acc; }
}

// ------- K2: scores s[h][t] = qh.k_cache[t,h]; 16 tokens/wave, 64B writes ----
__global__ void k_scores(const float* __restrict__ kc, const float* __restrict__ q,
                         float* __restrict__ s, unsigned* __restrict__ umin,
                         unsigned* __restrict__ umax) {
    __shared__ float sc_l[4][16][17];
    __shared__ float smn[4][16], smx[4][16];
    int wave = threadIdx.x >> 6, lane = threadIdx.x & 63;
    int wid = blockIdx.x * 4 + wave;           // 0..4095
    int t0 = wid * 16;
    const float4* q4 = (const float4*)q;
    float4 qv[4];
#pragma unroll
    for (int i = 0; i < 4; ++i) qv[i] = q4[i * 64 + lane];
    float mnv[4] = {3.4e38f, 3.4e38f, 3.4e38f, 3.4e38f};
    float mxv[4] = {-3.4e38f, -3.4e38f, -3.4e38f, -3.4e38f};
    for (int tt = 0; tt < 16; ++tt) {
        const float4* row = (const float4*)(kc + (size_t)(t0 + tt) * C);
        float acc[4];
#pragma unroll
        for (int i = 0; i < 4; ++i) {
            float4 a = row[i * 64 + lane];
            acc[i] = a.x * qv[i].x + a.y * qv[i].y + a.z * qv[i].z + a.w * qv[i].w;
        }
#pragma unroll
        for (int off = 8; off; off >>= 1) {
#pragma unroll
            for (int i = 0; i < 4; ++i) acc[i] += __shfl_xor(acc[i], off);
        }
        if ((lane & 15) == 0) {
            int g = lane >> 4;
#pragma unroll
            for (int i = 0; i < 4; ++i) {
                sc_l[wave][4 * i + g][tt] = acc[i];
                mnv[i] = fminf(mnv[i], acc[i]);
                mxv[i] = fmaxf(mxv[i], acc[i]);
            }
        }
    }
    __syncthreads();
    int tt2 = lane & 15;
#pragma unroll
    for (int r = 0; r < 4; ++r) {
        int h = r * 4 + (lane >> 4);
        s[(size_t)h * CT + t0 + tt2] = sc_l[wave][h][tt2];
    }
    if (blockIdx.x < 960) {                     // all 4 waves fully in PAST region
        if ((lane & 15) == 0) {
            int g = lane >> 4;
#pragma unroll
            for (int i = 0; i < 4; ++i) { smn[wave][4 * i + g] = mnv[i]; smx[wave][4 * i + g] = mxv[i]; }
        }
        __syncthreads();
        if (threadIdx.x < 16) {
            int h = threadIdx.x;
            float mn = smn[0][h], mx = smx[0][h];
            for (int w2 = 1; w2 < 4; ++w2) {
                mn = fminf(mn, smn[w2][h]);
                mx = fmaxf(mx, smx[w2][h]);
            }
            atomicMin(&umin[h], desc_key(mx));
            atomicMax(&umax[h], desc_key(mn));
        }
    }
}

// -------- K3 (mega): hist -> scan||winsum -> scatter -> rank -> attn -> out --
__global__ __launch_bounds__(1024, 2) void k_mega(
        const float* __restrict__ s, const float* __restrict__ vc,
        const unsigned* __restrict__ umin, const unsigned* __restrict__ umax,
        unsigned* __restrict__ base, unsigned* __restrict__ Tarr,
        ull* __restrict__ G, unsigned* __restrict__ stok,
        ull* __restrict__ cs_fix, float* __restrict__ part,
        const float* __restrict__ q, const float* __restrict__ kn,
        const float* __restrict__ vn, const float* __restrict__ Wo,
        float* __restrict__ out, unsigned* __restrict__ bar) {
    const int bid = blockIdx.x, tid = threadIdx.x;
    const int lane = tid & 63, wave = tid >> 6;
    __shared__ __align__(16) char smem[40960];
    __shared__ unsigned tarr_l[16];
    __shared__ unsigned shT, shN;

    // ---- Phase C: histogram (16 blocks/head; LDS hist -> device atomicAdd)
    {
        unsigned* lh = (unsigned*)smem;
        int h = bid >> 4, seg = bid & 15;
        for (int i = tid; i < NB; i += 1024) lh[i] = 0;
        __syncthreads();
        float hi, sc; load_params(umin, umax, h, &hi, &sc);
        const float* sh = s + (size_t)h * CT + seg * 3840;
        for (int i = tid; i < 3840; i += 1024)
            atomicAdd(&lh[bin_of(sh[i], hi, sc)], 1u);
        __syncthreads();
        unsigned* gh = base + h * NB;
        for (int i = tid; i < NB; i += 1024) {
            unsigned c = lh[i];
            if (c) atomicAdd(&gh[i], c);
        }
    }
    gsync(bar, 0);

    // ---- Phase D: scan+threshold (blocks 0..15; scoped base) || window sums
    if (bid < 16) {
        unsigned* wsum = (unsigned*)smem;
        unsigned* B = base + bid * NB;
        unsigned cnt[8];
        unsigned loc = 0;
        int b0 = tid * 8;
#pragma unroll
        for (int k = 0; k < 8; ++k) { cnt[k] = LD_A(&B[b0 + k]); loc += cnt[k]; }
        unsigned run = loc;
#pragma unroll
        for (int off = 1; off < 64; off <<= 1) {
            unsigned n = __shfl_up(run, off);
            if (lane >= off) run += n;
        }
        if (lane == 63) wsum[wave] = run;
        __syncthreads();
        if (wave == 0 && lane < 16) {
            unsigned v = wsum[lane];
#pragma unroll
            for (int off = 1; off < 16; off <<= 1) {
                unsigned n = __shfl_up(v, off);
                if (lane >= off) v += n;
            }
            wsum[lane] = v;
        }
        __syncthreads();
        unsigned r = run - loc + (wave ? wsum[wave - 1] : 0u);
#pragma unroll
        for (int k = 0; k < 8; ++k) {
            unsigned c = cnt[k];
            ST_A(&B[b0 + k], r);
            unsigned inc = r + c;
            if (r < KEEP && inc >= KEEP) ST_A(&Tarr[bid], (unsigned)(b0 + k));
            r = inc;
        }
    } else {
        int gw = (bid - 16) * 16 + wave;        // 0..3839
        if (gw < NH * 64) {
            int h = gw >> 6, c2 = gw & 63;
            float v = s[(size_t)h * CT + PAST + c2 * 64 + lane];
            long long f = llrintf(v * 16777216.f);
#pragma unroll
            for (int off = 32; off; off >>= 1) f += __shfl_xor(f, off);
            if (lane == 0) atomicAdd(&cs_fix[NCOMP + c2], (ull)f);
        }
    }
    gsync(bar, 1);

    // ---- Phase E: scatter candidates (bins <= T); G via scoped stores
    if (tid < 16) tarr_l[tid] = LD_A(&Tarr[tid]);
    __syncthreads();
    for (int i = bid * 1024 + tid; i < NH * PAST; i += NBLK * 1024) {
        int h = i / PAST, t = i - h * PAST;
        float hi, sc; load_params(umin, umax, h, &hi, &sc);
        float v = s[(size_t)h * CT + t];
        int b = bin_of(v, hi, sc);
        if ((unsigned)b <= tarr_l[h]) {
            unsigned pos = atomicAdd(&base[h * NB + b], 1u);
            ST_A(&G[(size_t)h * 65536 + pos], ((ull)desc_key(v) << 16) | (unsigned)t);
        }
    }
    gsync(bar, 2);

    // ---- Phase F: exact rank within bin (plain G reads; scoped base/stok)
    {
        ull* csl = (ull*)smem;
        if (tid < NCOMP) csl[tid] = 0ull;
        int h = bid >> 4, seg = bid & 15;
        if (tid == 0) {
            unsigned T = LD_A(&Tarr[h]);
            shT = T;
            shN = LD_A(&base[h * NB + T]);      // post-scatter inclusive end of T
        }
        __syncthreads();
        float hi, sc; load_params(umin, umax, h, &hi, &sc);
        unsigned ncand = shN;
        const ull* Gh = G + (size_t)h * 65536;
        for (unsigned p = seg * 1024 + tid; p < ncand; p += 16384) {
            ull pk = Gh[p];
            unsigned u = (unsigned)(pk >> 16);
            float v = u_to_f(u);
            int b = bin_of(v, hi, sc);
            unsigned start = b ? LD_A(&base[h * NB + b - 1]) : 0u;
            unsigned end = LD_A(&base[h * NB + b]);
            unsigned rank = start;
            for (unsigned j = start; j < end; ++j) rank += (Gh[j] < pk) ? 1u : 0u;
            if (rank < KEEP) {
                ST_A(&stok[h * KEEP + rank], (unsigned)(pk & 0xFFFFull));
                long long f = llrintf(v * 16777216.f);
                atomicAdd(&csl[rank >> 6], (ull)f);
            }
        }
        __syncthreads();
        if (tid < NCOMP) {
            ull c = csl[tid];
            if (c) atomicAdd(&cs_fix[tid], c);
        }
    }
    gsync(bar, 3);

    // ---- Phase H: top-32 (redundant/block) + partial softmax+PV (2 pairs/blk)
    {
        ull* key = (ull*)smem;                       // 2048 B
        unsigned* sel_l = (unsigned*)(smem + 2048);  // 128 B
        float* scm = (float*)(smem + 2176);          // 512 B (2x64)
        float* exb = (float*)(smem + 2688);          // 512 B (2x64)
        float* vbuf = (float*)(smem + 3200);         // 2 x 64 x 68 floats
        if (tid < 256) {
            long long v = (long long)cs_fix[tid];    // plain: first touch post-F
            ull bb = (ull)(v + (1ll << 45));
            key[tid] = (((1ull << 46) - bb) << 8) | (unsigned)tid;
        }
        __syncthreads();
        for (unsigned k = 2; k <= 256; k <<= 1) {
            for (unsigned j = k >> 1; j > 0; j >>= 1) {
                if (tid < 256) {
                    unsigned ixj = tid ^ j;
                    if (ixj > (unsigned)tid) {
                        ull a = key[tid], b = key[ixj];
                        bool up = ((tid & k) == 0);
                        if (up ? (a > b) : (a < b)) { key[tid] = b; key[ixj] = a; }
                    }
                }
                __syncthreads();
            }
        }
        if (tid < NSEL) sel_l[tid] = (unsigned)(key[tid] & 0xFFull);
        __syncthreads();

        int su = tid >> 9, sid = tid & 511;
        int p = bid * 2 + su;                    // 0..511
        int h = p >> 5, ci = p & 31;
        int c = (int)sel_l[ci];
        int g = sid >> 3, q8 = sid & 7;
        int t = (c < NCOMP) ? (int)stok[h * KEEP + c * 64 + g]   // plain: first touch
                            : (PAST + (c - NCOMP) * 64 + g);
        if (q8 == 0) scm[su * 64 + g] = s[(size_t)h * CT + t] * 0.125f;
        __syncthreads();
        float m = -1e30f;
        for (int j = 0; j < 64; ++j) m = fmaxf(m, scm[su * 64 + j]);
        float e = expf(scm[su * 64 + g] - m);
        if (q8 == 0) exb[su * 64 + g] = e;
        const float4* vrow = (const float4*)(vc + (size_t)t * C + h * HS);
        float4 v0 = vrow[q8 * 2], v1 = vrow[q8 * 2 + 1];
        float* vb = vbuf + su * 4352 + g * 68 + q8 * 8;
        vb[0] = e * v0.x; vb[1] = e * v0.y; vb[2] = e * v0.z; vb[3] = e * v0.w;
        vb[4] = e * v1.x; vb[5] = e * v1.y; vb[6] = e * v1.z; vb[7] = e * v1.w;
        __syncthreads();
        if (sid < 64) {
            float acc = 0.f;
            for (int g2 = 0; g2 < 64; ++g2) acc += vbuf[su * 4352 + g2 * 68 + sid];
            float* P = part + (size_t)(h * 32 + ci) * 68;
            ST_A(&P[2 + sid], acc);
            if (sid == 0) {
                float es = 0.f;
                for (int g2 = 0; g2 < 64; ++g2) es += exb[su * 64 + g2];
                ST_A(&P[0], m);
                ST_A(&P[1], es);
            }
        }
    }
    gsync(bar, 4);
    if (bid >= 64) return;

    // ---- Phase J: combine partials -> y (LDS, redundant) -> out = y @ Wo.T
    {
        float* yl = (float*)smem;                 // 4 KB
        float* qdl = (float*)(smem + 4096);       // 64 B
        if (tid < 16) {
            float qd = 0.f;
            for (int l = 0; l < 64; ++l) qd += q[tid * 64 + l] * kn[tid * 64 + l];
            qdl[tid] = qd;
        }
        __syncthreads();
        {
            int h = tid >> 6, ln = tid & 63;
            float a_new = qdl[h] * 0.125f;
            const float* P0 = part + (size_t)h * 32 * 68;   // plain: first touch
            float m = a_new;
            for (int ci = 0; ci < 32; ++ci) m = fmaxf(m, P0[ci * 68]);
            float den = expf(a_new - m);
            float acc = den * vn[h * HS + ln];
            for (int ci = 0; ci < 32; ++ci) {
                float w = expf(P0[ci * 68] - m);
                den += w * P0[ci * 68 + 1];
                acc += w * P0[ci * 68 + 2 + ln];
            }
            yl[tid] = acc / den;
        }
        __syncthreads();
        int r = bid * 16 + wave;                  // 0..1023
        const float4* Wrow = (const float4*)(Wo + (size_t)r * C);
        const float4* y4 = (const float4*)yl;
        float acc = 0.f;
#pragma unroll
        for (int i = 0; i < 4; ++i) {
            float4 a = Wrow[i * 64 + lane];
            float4 b = y4[i * 64 + lane];
            acc += a.x * b.x + a.y * b.y + a.z * b.z + a.w * b.w;
        }
#pragma unroll
        for (int off = 32; off; off >>= 1) acc += __shfl_xor(acc, off);
        if (lane == 0) out[r] = acc;
    }
}

extern "C" void kernel_launch(void* const* d_in, const int* in_sizes, int n_in,
                              void* d_out, int out_size, void* d_ws, size_t ws_size,
                              hipStream_t stream) {
    const float* x  = (const float*)d_in[0];
    const float* kc = (const float*)d_in[1];
    const float* vc = (const float*)d_in[2];
    const float* Wr = (const float*)d_in[3];
    const float* Wk = (const float*)d_in[4];
    const float* Wv = (const float*)d_in[5];
    const float* Wo = (const float*)d_in[6];
    float* out = (float*)d_out;
    char* ws = (char*)d_ws;

    float* q    = (float*)(ws + 0);
    float* kn   = (float*)(ws + 8192);
    float* vn   = (float*)(ws + 16384);
    ull* cs_fix = (ull*)(ws + 32768);                  // 2 KiB
    float* part = (float*)(ws + 49152);                // 139264 B
    unsigned* stok = (unsigned*)(ws + 196608);         // 16*12288*4 = 786432 B
    unsigned* umin = (unsigned*)(ws + 1048576);
    unsigned* umax = (unsigned*)(ws + 1048640);
    unsigned* Tarr = (unsigned*)(ws + 1048704);
    unsigned* bar  = (unsigned*)(ws + 1048832);        // 8 KiB (5 sites x 288 u32)
    unsigned* base = (unsigned*)(ws + 1114112);        // 512 KiB
    float* s = (float*)(ws + 2097152);                 // 4 MiB
    ull* G = (ull*)(ws + 6291456);                     // 8 MiB

    k_proj<<<768, 256, 0, stream>>>(x, Wr, Wk, Wv, q, kn, vn, base, umin, umax, cs_fix, bar);
    k_scores<<<1024, 256, 0, stream>>>(kc, q, s, umin, umax);
    k_mega<<<NBLK, 1024, 0, stream>>>(s, vc, umin, umax, base, Tarr, G, stok, cs_fix,
                                      part, q, kn, vn, Wo, out, bar);
}

// Round 12
// 130.449 us; speedup vs baseline: 1.6878x; 1.0994x over previous
//
#include <hip/hip_runtime.h>
#include <stdint.h>

#define C      1024
#define NH     16
#define HS     64
#define CT     65536
#define PAST   61440   // CT - WINDOW
#define KEEP   12288   // MIN_KV - WINDOW
#define NCOMP  192     // KEEP/64
#define NSEL   32
#define NB     8192    // selection bins
#define NBLK   256     // mega-kernel grid (1 block/CU, co-resident)

typedef unsigned long long ull;

// agent-scope relaxed accessors: write-through / fresh-read at coherence point
#define LD_A(p)   __hip_atomic_load((p), __ATOMIC_RELAXED, __HIP_MEMORY_SCOPE_AGENT)
#define ST_A(p,v) __hip_atomic_store((p), (v), __ATOMIC_RELAXED, __HIP_MEMORY_SCOPE_AGENT)

// monotone transform: larger float => smaller u (asc u == desc value)
__device__ __forceinline__ unsigned int desc_key(float f) {
    unsigned int b = __float_as_uint(f);
    return (b >> 31) ? b : (~b & 0x7FFFFFFFu);
}
__device__ __forceinline__ float u_to_f(unsigned int u) {
    unsigned int b = (u & 0x80000000u) ? u : (0x7FFFFFFFu - u);
    return __uint_as_float(b);
}
// monotone linear bin: s descending <-> bin ascending
__device__ __forceinline__ int bin_of(float s, float hi, float scale) {
    int b = (int)((hi - s) * scale);
    return b < 0 ? 0 : (b > NB - 1 ? NB - 1 : b);
}
__device__ __forceinline__ void load_params(const unsigned* umin, const unsigned* umax,
                                            int h, float* hi, float* sc) {
    float h2 = u_to_f(umin[h]);
    float lo = u_to_f(umax[h]);
    float r = h2 - lo;
    *hi = h2;
    *sc = (r > 0.f) ? (float)(NB - 1) / r : 0.f;
}

// fence-free barriers (validated R11): vmcnt drain + relaxed arrivals + poll.
// global (256 blocks, hierarchical): sites 0..1 at bar[site*288 .. +288)
__device__ __forceinline__ void gsync(unsigned* bar, int site) {
    __syncthreads();
    if (threadIdx.x == 0) {
        asm volatile("s_waitcnt vmcnt(0)" ::: "memory");
        unsigned* g    = bar + site * 288 + (blockIdx.x >> 5) * 32;
        unsigned* root = bar + site * 288 + 256;
        if (__hip_atomic_fetch_add(g, 1u, __ATOMIC_RELAXED, __HIP_MEMORY_SCOPE_AGENT) == 31u)
            __hip_atomic_fetch_add(root, 1u, __ATOMIC_RELAXED, __HIP_MEMORY_SCOPE_AGENT);
        while (LD_A(root) < 8u) __builtin_amdgcn_s_sleep(16);
    }
    __syncthreads();
}
// per-head (16 blocks): sites at bar[576 + (site*16+h)*32]
__device__ __forceinline__ void hsync(unsigned* bar, int site, int h) {
    __syncthreads();
    if (threadIdx.x == 0) {
        asm volatile("s_waitcnt vmcnt(0)" ::: "memory");
        unsigned* c = bar + 576 + (site * 16 + h) * 32;
        __hip_atomic_fetch_add(c, 1u, __ATOMIC_RELAXED, __HIP_MEMORY_SCOPE_AGENT);
        while (LD_A(c) < 16u) __builtin_amdgcn_s_sleep(8);
    }
    __syncthreads();
}

// ---------------- K1: q/k/v projections + all zero-inits ---------------------
__global__ void k_proj(const float* __restrict__ x, const float* __restrict__ Wr,
                       const float* __restrict__ Wk, const float* __restrict__ Wv,
                       float* __restrict__ q, float* __restrict__ kn, float* __restrict__ vn,
                       unsigned* __restrict__ hc, unsigned* __restrict__ umin,
                       unsigned* __restrict__ umax, ull* __restrict__ cs_fix,
                       unsigned* __restrict__ bar) {
    int gid = blockIdx.x * 256 + threadIdx.x;       // 0..196607
    for (int i = gid; i < 2 * NH * NB; i += 196608) hc[i] = 0;   // hist + cnt
    if (blockIdx.x >= 512 && blockIdx.x < 520)
        bar[(blockIdx.x - 512) * 256 + threadIdx.x] = 0u;        // 2048 u32
    if (blockIdx.x == 700) {
        if (threadIdx.x < 16) umin[threadIdx.x] = 0xFFFFFFFFu;
        else if (threadIdx.x < 32) umax[threadIdx.x - 16] = 0u;
    }
    if (blockIdx.x == 701 && threadIdx.x < 256) cs_fix[threadIdx.x] = 0ull;

    int w = blockIdx.x * (blockDim.x >> 6) + (threadIdx.x >> 6); // 0..3071
    int lane = threadIdx.x & 63;
    int mat = w >> 10, row = w & 1023;
    const float* W = (mat == 0) ? Wr : (mat == 1) ? Wk : Wv;
    const float4* Wrow = (const float4*)(W + (size_t)row * C);
    const float4* x4 = (const float4*)x;
    float acc = 0.f;
#pragma unroll
    for (int i = 0; i < 4; ++i) {
        float4 a = Wrow[i * 64 + lane];
        float4 b = x4[i * 64 + lane];
        acc += a.x * b.x + a.y * b.y + a.z * b.z + a.w * b.w;
    }
#pragma unroll
    for (int off = 32; off; off >>= 1) acc += __shfl_xor(acc, off);
    if (lane == 0) { (mat == 0 ? q : (mat == 1 ? kn : vn))[row] = acc; }
}

// -- K2: scores; 16 tokens/wave; minmax (PAST blocks) / chunk sums (window) ---
__global__ void k_scores(const float* __restrict__ kc, const float* __restrict__ q,
                         float* __restrict__ s, unsigned* __restrict__ umin,
                         unsigned* __restrict__ umax, ull* __restrict__ cs_fix) {
    __shared__ float sc_l[4][16][17];
    __shared__ float smn[4][16], smx[4][16];
    __shared__ long long wred[4];
    int wave = threadIdx.x >> 6, lane = threadIdx.x & 63;
    int wid = blockIdx.x * 4 + wave;           // 0..4095
    int t0 = wid * 16;
    const float4* q4 = (const float4*)q;
    float4 qv[4];
#pragma unroll
    for (int i = 0; i < 4; ++i) qv[i] = q4[i * 64 + lane];
    float mnv[4] = {3.4e38f, 3.4e38f, 3.4e38f, 3.4e38f};
    float mxv[4] = {-3.4e38f, -3.4e38f, -3.4e38f, -3.4e38f};
    for (int tt = 0; tt < 16; ++tt) {
        const float4* row = (const float4*)(kc + (size_t)(t0 + tt) * C);
        float acc[4];
#pragma unroll
        for (int i = 0; i < 4; ++i) {
            float4 a = row[i * 64 + lane];
            acc[i] = a.x * qv[i].x + a.y * qv[i].y + a.z * qv[i].z + a.w * qv[i].w;
        }
#pragma unroll
        for (int off = 8; off; off >>= 1) {
#pragma unroll
            for (int i = 0; i < 4; ++i) acc[i] += __shfl_xor(acc[i], off);
        }
        if ((lane & 15) == 0) {
            int g = lane >> 4;
#pragma unroll
            for (int i = 0; i < 4; ++i) {
                sc_l[wave][4 * i + g][tt] = acc[i];
                mnv[i] = fminf(mnv[i], acc[i]);
                mxv[i] = fmaxf(mxv[i], acc[i]);
            }
        }
    }
    __syncthreads();
    int tt2 = lane & 15;
#pragma unroll
    for (int r = 0; r < 4; ++r) {
        int h = r * 4 + (lane >> 4);
        s[(size_t)h * CT + t0 + tt2] = sc_l[wave][h][tt2];
    }
    if (blockIdx.x < 960) {                     // PAST region: per-head min/max
        if ((lane & 15) == 0) {
            int g = lane >> 4;
#pragma unroll
            for (int i = 0; i < 4; ++i) { smn[wave][4 * i + g] = mnv[i]; smx[wave][4 * i + g] = mxv[i]; }
        }
        __syncthreads();
        if (threadIdx.x < 16) {
            int h = threadIdx.x;
            float mn = smn[0][h], mx = smx[0][h];
            for (int w2 = 1; w2 < 4; ++w2) {
                mn = fminf(mn, smn[w2][h]);
                mx = fmaxf(mx, smx[w2][h]);
            }
            atomicMin(&umin[h], desc_key(mx));
            atomicMax(&umax[h], desc_key(mn));
        }
    } else {                                    // window: this block == 1 chunk
        int hh = threadIdx.x >> 4, tt = threadIdx.x & 15;
        long long f = 0;
#pragma unroll
        for (int w2 = 0; w2 < 4; ++w2) f += llrintf(sc_l[w2][hh][tt] * 16777216.f);
#pragma unroll
        for (int off = 32; off; off >>= 1) f += __shfl_xor(f, off);
        if (lane == 0) wred[wave] = f;
        __syncthreads();
        if (threadIdx.x == 0)
            cs_fix[NCOMP + (blockIdx.x - 960)] =
                (ull)(wred[0] + wred[1] + wred[2] + wred[3]);
    }
}

// -------- K3 (mega): per-head {hist -> scan+scatter -> rank} -> attn -> out --
__global__ __launch_bounds__(1024, 2) void k_mega(
        const float* __restrict__ s, const float* __restrict__ vc,
        const unsigned* __restrict__ umin, const unsigned* __restrict__ umax,
        unsigned* __restrict__ hist, unsigned* __restrict__ cnt,
        ull* __restrict__ G, unsigned* __restrict__ stok,
        ull* __restrict__ cs_fix, float* __restrict__ part,
        const float* __restrict__ q, const float* __restrict__ kn,
        const float* __restrict__ vn, const float* __restrict__ Wo,
        float* __restrict__ out, unsigned* __restrict__ bar) {
    const int bid = blockIdx.x, tid = threadIdx.x;
    const int lane = tid & 63, wave = tid >> 6;
    const int h = bid >> 4, seg = bid & 15;
    __shared__ __align__(16) char smem[40960];
    __shared__ unsigned shT, shN;
    __shared__ unsigned wsum[16];

    float hi, sc; load_params(umin, umax, h, &hi, &sc);
    unsigned* lh = (unsigned*)smem;             // 32 KB: hist, then scan bases

    // ---- Phase C: histogram (16 blocks/head; LDS hist -> device atomicAdd)
    {
        for (int i = tid; i < NB; i += 1024) lh[i] = 0;
        __syncthreads();
        const float* sh = s + (size_t)h * CT + seg * 3840;
        for (int i = tid; i < 3840; i += 1024)
            atomicAdd(&lh[bin_of(sh[i], hi, sc)], 1u);
        __syncthreads();
        unsigned* gh = hist + h * NB;
        for (int i = tid; i < NB; i += 1024) {
            unsigned c = lh[i];
            if (c) atomicAdd(&gh[i], c);
        }
    }
    hsync(bar, 0, h);

    // ---- Scan (redundant in every block): lh = exclusive bases; T, ncand
    {
        const unsigned* gh = hist + h * NB;
        unsigned c8[8]; unsigned loc = 0; int b0 = tid * 8;
#pragma unroll
        for (int k = 0; k < 8; ++k) { c8[k] = gh[b0 + k]; loc += c8[k]; }
        unsigned run = loc;
#pragma unroll
        for (int off = 1; off < 64; off <<= 1) {
            unsigned n = __shfl_up(run, off);
            if (lane >= off) run += n;
        }
        if (lane == 63) wsum[wave] = run;
        __syncthreads();
        if (wave == 0 && lane < 16) {
            unsigned v = wsum[lane];
#pragma unroll
            for (int off = 1; off < 16; off <<= 1) {
                unsigned n = __shfl_up(v, off);
                if (lane >= off) v += n;
            }
            wsum[lane] = v;
        }
        __syncthreads();
        unsigned r = run - loc + (wave ? wsum[wave - 1] : 0u);
#pragma unroll
        for (int k = 0; k < 8; ++k) {
            unsigned c = c8[k];
            lh[b0 + k] = r;
            unsigned inc = r + c;
            if (r < KEEP && inc >= KEEP) { shT = (unsigned)(b0 + k); shN = inc; }
            r = inc;
        }
    }
    __syncthreads();
    const unsigned T = shT, ncand = shN;

    // ---- Scatter: static layout pos = lds_base[b] + ticket(cnt)
    {
        const float* sh = s + (size_t)h * CT + seg * 3840;
        unsigned* ch = cnt + h * NB;
        ull* Gh = G + (size_t)h * 65536;
        for (int i = tid; i < 3840; i += 1024) {
            float v = sh[i];
            int b = bin_of(v, hi, sc);
            if ((unsigned)b <= T) {
                unsigned pos = lh[b] + atomicAdd(&ch[b], 1u);
                ST_A(&Gh[pos], ((ull)desc_key(v) << 16) | (unsigned)(seg * 3840 + i));
            }
        }
    }
    hsync(bar, 1, h);

    // ---- Phase F: exact rank (static bin bounds from LDS scan)
    {
        ull* csl = (ull*)(smem + 32768);        // 1.5 KB, disjoint from lh
        if (tid < NCOMP) csl[tid] = 0ull;
        __syncthreads();
        const ull* Gh = G + (size_t)h * 65536;
        for (unsigned p = seg * 1024 + tid; p < ncand; p += 16384) {
            ull pk = Gh[p];
            unsigned u = (unsigned)(pk >> 16);
            float v = u_to_f(u);
            int b = bin_of(v, hi, sc);
            unsigned start = lh[b];
            unsigned end = (b == NB - 1) ? ncand : lh[b + 1];
            unsigned rank = start;
            for (unsigned j = start; j < end; ++j) rank += (Gh[j] < pk) ? 1u : 0u;
            if (rank < KEEP) {
                ST_A(&stok[h * KEEP + rank], (unsigned)(pk & 0xFFFFull));
                long long f = llrintf(v * 16777216.f);
                atomicAdd(&csl[rank >> 6], (ull)f);
            }
        }
        __syncthreads();
        if (tid < NCOMP) {
            ull c = csl[tid];
            if (c) atomicAdd(&cs_fix[tid], c);
        }
    }
    gsync(bar, 0);

    // ---- Phase H: top-32 (redundant/block) + partial softmax+PV (2 pairs/blk)
    {
        ull* key = (ull*)smem;                       // 2048 B
        unsigned* sel_l = (unsigned*)(smem + 2048);  // 128 B
        float* scm = (float*)(smem + 2176);          // 512 B (2x64)
        float* exb = (float*)(smem + 2688);          // 512 B (2x64)
        float* vbuf = (float*)(smem + 3200);         // 2 x 64 x 68 floats
        if (tid < 256) {
            long long v = (long long)cs_fix[tid];    // plain: first touch post-F
            ull bb = (ull)(v + (1ll << 45));
            key[tid] = (((1ull << 46) - bb) << 8) | (unsigned)tid;
        }
        __syncthreads();
        for (unsigned k = 2; k <= 256; k <<= 1) {
            for (unsigned j = k >> 1; j > 0; j >>= 1) {
                if (tid < 256) {
                    unsigned ixj = tid ^ j;
                    if (ixj > (unsigned)tid) {
                        ull a = key[tid], b = key[ixj];
                        bool up = ((tid & k) == 0);
                        if (up ? (a > b) : (a < b)) { key[tid] = b; key[ixj] = a; }
                    }
                }
                __syncthreads();
            }
        }
        if (tid < NSEL) sel_l[tid] = (unsigned)(key[tid] & 0xFFull);
        __syncthreads();

        int su = tid >> 9, sid = tid & 511;
        int p = bid * 2 + su;                    // 0..511
        int hh = p >> 5, ci = p & 31;
        int c = (int)sel_l[ci];
        int g = sid >> 3, q8 = sid & 7;
        int t = (c < NCOMP) ? (int)stok[hh * KEEP + c * 64 + g]   // plain: first touch
                            : (PAST + (c - NCOMP) * 64 + g);
        if (q8 == 0) scm[su * 64 + g] = s[(size_t)hh * CT + t] * 0.125f;
        __syncthreads();
        float m = -1e30f;
        for (int j = 0; j < 64; ++j) m = fmaxf(m, scm[su * 64 + j]);
        float e = expf(scm[su * 64 + g] - m);
        if (q8 == 0) exb[su * 64 + g] = e;
        const float4* vrow = (const float4*)(vc + (size_t)t * C + hh * HS);
        float4 v0 = vrow[q8 * 2], v1 = vrow[q8 * 2 + 1];
        float* vb = vbuf + su * 4352 + g * 68 + q8 * 8;
        vb[0] = e * v0.x; vb[1] = e * v0.y; vb[2] = e * v0.z; vb[3] = e * v0.w;
        vb[4] = e * v1.x; vb[5] = e * v1.y; vb[6] = e * v1.z; vb[7] = e * v1.w;
        __syncthreads();
        if (sid < 64) {
            float acc = 0.f;
            for (int g2 = 0; g2 < 64; ++g2) acc += vbuf[su * 4352 + g2 * 68 + sid];
            float* P = part + (size_t)(hh * 32 + ci) * 68;
            ST_A(&P[2 + sid], acc);
            if (sid == 0) {
                float es = 0.f;
                for (int g2 = 0; g2 < 64; ++g2) es += exb[su * 64 + g2];
                ST_A(&P[0], m);
                ST_A(&P[1], es);
            }
        }
    }
    gsync(bar, 1);
    if (bid >= 64) return;

    // ---- Phase J: combine partials -> y (LDS, redundant) -> out = y @ Wo.T
    {
        float* yl = (float*)smem;                 // 4 KB
        float* qdl = (float*)(smem + 4096);       // 64 B
        if (tid < 16) {
            float qd = 0.f;
            for (int l = 0; l < 64; ++l) qd += q[tid * 64 + l] * kn[tid * 64 + l];
            qdl[tid] = qd;
        }
        __syncthreads();
        {
            int hh = tid >> 6, ln = tid & 63;
            float a_new = qdl[hh] * 0.125f;
            const float* P0 = part + (size_t)hh * 32 * 68;   // plain: first touch
            float m = a_new;
            for (int ci = 0; ci < 32; ++ci) m = fmaxf(m, P0[ci * 68]);
            float den = expf(a_new - m);
            float acc = den * vn[hh * HS + ln];
            for (int ci = 0; ci < 32; ++ci) {
                float w = expf(P0[ci * 68] - m);
                den += w * P0[ci * 68 + 1];
                acc += w * P0[ci * 68 + 2 + ln];
            }
            yl[tid] = acc / den;
        }
        __syncthreads();
        int r = bid * 16 + wave;                  // 0..1023
        const float4* Wrow = (const float4*)(Wo + (size_t)r * C);
        const float4* y4 = (const float4*)yl;
        float acc = 0.f;
#pragma unroll
        for (int i = 0; i < 4; ++i) {
            float4 a = Wrow[i * 64 + lane];
            float4 b = y4[i * 64 + lane];
            acc += a.x * b.x + a.y * b.y + a.z * b.z + a.w * b.w;
        }
#pragma unroll
        for (int off = 32; off; off >>= 1) acc += __shfl_xor(acc, off);
        if (lane == 0) out[r] = acc;
    }
}

extern "C" void kernel_launch(void* const* d_in, const int* in_sizes, int n_in,
                              void* d_out, int out_size, void* d_ws, size_t ws_size,
                              hipStream_t stream) {
    const float* x  = (const float*)d_in[0];
    const float* kc = (const float*)d_in[1];
    const float* vc = (const float*)d_in[2];
    const float* Wr = (const float*)d_in[3];
    const float* Wk = (const float*)d_in[4];
    const float* Wv = (const float*)d_in[5];
    const float* Wo = (const float*)d_in[6];
    float* out = (float*)d_out;
    char* ws = (char*)d_ws;

    float* q    = (float*)(ws + 0);
    float* kn   = (float*)(ws + 8192);
    float* vn   = (float*)(ws + 16384);
    ull* cs_fix = (ull*)(ws + 32768);                  // 2 KiB
    float* part = (float*)(ws + 49152);                // 139264 B
    unsigned* stok = (unsigned*)(ws + 196608);         // 786432 B
    unsigned* umin = (unsigned*)(ws + 1048576);
    unsigned* umax = (unsigned*)(ws + 1048640);
    unsigned* bar  = (unsigned*)(ws + 1048832);        // 8 KiB counters
    unsigned* hist = (unsigned*)(ws + 1114112);        // 512 KiB
    unsigned* cnt  = (unsigned*)(ws + 1638400);        // 512 KiB (scatter tickets)
    float* s = (float*)(ws + 2621440);                 // 4 MiB
    ull* G = (ull*)(ws + 7340032);                     // 8 MiB

    k_proj<<<768, 256, 0, stream>>>(x, Wr, Wk, Wv, q, kn, vn, hist, umin, umax, cs_fix, bar);
    k_scores<<<1024, 256, 0, stream>>>(kc, q, s, umin, umax, cs_fix);
    k_mega<<<NBLK, 1024, 0, stream>>>(s, vc, umin, umax, hist, cnt, G, stok, cs_fix,
                                      part, q, kn, vn, Wo, out, bar);
}

// Round 13
// 123.990 us; speedup vs baseline: 1.7757x; 1.0521x over previous
//
#include <hip/hip_runtime.h>
#include <stdint.h>

#define C      1024
#define NH     16
#define HS     64
#define CT     65536
#define PAST   61440   // CT - WINDOW
#define KEEP   12288   // MIN_KV - WINDOW
#define NCOMP  192     // KEEP/64
#define NSEL   32
#define NB     8192    // selection bins
#define NBLK   256     // mega-kernel grid (1 block/CU, co-resident)
#define FLAGW  8       // u32 stride between per-block flags (32 B lines)

typedef unsigned long long ull;

// agent-scope relaxed accessors: write-through / fresh-read at coherence point
#define LD_A(p)   __hip_atomic_load((p), __ATOMIC_RELAXED, __HIP_MEMORY_SCOPE_AGENT)
#define ST_A(p,v) __hip_atomic_store((p), (v), __ATOMIC_RELAXED, __HIP_MEMORY_SCOPE_AGENT)

// monotone transform: larger float => smaller u (asc u == desc value)
__device__ __forceinline__ unsigned int desc_key(float f) {
    unsigned int b = __float_as_uint(f);
    return (b >> 31) ? b : (~b & 0x7FFFFFFFu);
}
__device__ __forceinline__ float u_to_f(unsigned int u) {
    unsigned int b = (u & 0x80000000u) ? u : (0x7FFFFFFFu - u);
    return __uint_as_float(b);
}
// monotone linear bin: s descending <-> bin ascending
__device__ __forceinline__ int bin_of(float s, float hi, float scale) {
    int b = (int)((hi - s) * scale);
    return b < 0 ? 0 : (b > NB - 1 ? NB - 1 : b);
}
__device__ __forceinline__ void load_params(const unsigned* umin, const unsigned* umax,
                                            int h, float* hi, float* sc) {
    float h2 = u_to_f(umin[h]);
    float lo = u_to_f(umax[h]);
    float r = h2 - lo;
    *hi = h2;
    *sc = (r > 0.f) ? (float)(NB - 1) / r : 0.f;
}

// store-based sense barriers (R13): arrival = one scoped STORE to the block's
// own padded flag line (no RMW serialization); wait = parallel polls of the
// relevant flag subset. Flags increase monotonically (phase 1..5 per launch).
// Preceding __syncthreads drains each wave's vmcnt (validated R11/R12), so all
// the block's write-through scoped stores are visible before the flag store.
__device__ __forceinline__ void arrive(unsigned* flag, unsigned ph) {
    __syncthreads();
    if (threadIdx.x == 0) {
        asm volatile("s_waitcnt vmcnt(0)" ::: "memory");
        ST_A(&flag[blockIdx.x * FLAGW], ph);
    }
}
__device__ __forceinline__ void wait_head(unsigned* flag, unsigned ph, int h) {
    if (threadIdx.x < 16)
        while (LD_A(&flag[(h * 16 + threadIdx.x) * FLAGW]) < ph)
            __builtin_amdgcn_s_sleep(2);
    __syncthreads();
}
__device__ __forceinline__ void wait_all(unsigned* flag, unsigned ph) {
    if (threadIdx.x < 256)
        while (LD_A(&flag[threadIdx.x * FLAGW]) < ph)
            __builtin_amdgcn_s_sleep(2);
    __syncthreads();
}

// ---------------- K1: q/k/v projections + all zero-inits ---------------------
__global__ void k_proj(const float* __restrict__ x, const float* __restrict__ Wr,
                       const float* __restrict__ Wk, const float* __restrict__ Wv,
                       float* __restrict__ q, float* __restrict__ kn, float* __restrict__ vn,
                       unsigned* __restrict__ hc, unsigned* __restrict__ umin,
                       unsigned* __restrict__ umax, ull* __restrict__ cs_fix,
                       unsigned* __restrict__ flag) {
    int gid = blockIdx.x * 256 + threadIdx.x;       // 0..196607
    for (int i = gid; i < 2 * NH * NB; i += 196608) hc[i] = 0;   // hist + cnt
    if (blockIdx.x >= 512 && blockIdx.x < 520)
        flag[(blockIdx.x - 512) * 256 + threadIdx.x] = 0u;       // 2048 u32
    if (blockIdx.x == 700) {
        if (threadIdx.x < 16) umin[threadIdx.x] = 0xFFFFFFFFu;
        else if (threadIdx.x < 32) umax[threadIdx.x - 16] = 0u;
    }
    if (blockIdx.x == 701 && threadIdx.x < 256) cs_fix[threadIdx.x] = 0ull;

    int w = blockIdx.x * (blockDim.x >> 6) + (threadIdx.x >> 6); // 0..3071
    int lane = threadIdx.x & 63;
    int mat = w >> 10, row = w & 1023;
    const float* W = (mat == 0) ? Wr : (mat == 1) ? Wk : Wv;
    const float4* Wrow = (const float4*)(W + (size_t)row * C);
    const float4* x4 = (const float4*)x;
    float acc = 0.f;
#pragma unroll
    for (int i = 0; i < 4; ++i) {
        float4 a = Wrow[i * 64 + lane];
        float4 b = x4[i * 64 + lane];
        acc += a.x * b.x + a.y * b.y + a.z * b.z + a.w * b.w;
    }
#pragma unroll
    for (int off = 32; off; off >>= 1) acc += __shfl_xor(acc, off);
    if (lane == 0) { (mat == 0 ? q : (mat == 1 ? kn : vn))[row] = acc; }
}

// -- K2: scores; 16 tokens/wave; minmax (PAST blocks) / chunk sums (window) ---
__global__ void k_scores(const float* __restrict__ kc, const float* __restrict__ q,
                         float* __restrict__ s, unsigned* __restrict__ umin,
                         unsigned* __restrict__ umax, ull* __restrict__ cs_fix) {
    __shared__ float sc_l[4][16][17];
    __shared__ float smn[4][16], smx[4][16];
    __shared__ long long wred[4];
    int wave = threadIdx.x >> 6, lane = threadIdx.x & 63;
    int wid = blockIdx.x * 4 + wave;           // 0..4095
    int t0 = wid * 16;
    const float4* q4 = (const float4*)q;
    float4 qv[4];
#pragma unroll
    for (int i = 0; i < 4; ++i) qv[i] = q4[i * 64 + lane];
    float mnv[4] = {3.4e38f, 3.4e38f, 3.4e38f, 3.4e38f};
    float mxv[4] = {-3.4e38f, -3.4e38f, -3.4e38f, -3.4e38f};
    for (int tt = 0; tt < 16; ++tt) {
        const float4* row = (const float4*)(kc + (size_t)(t0 + tt) * C);
        float acc[4];
#pragma unroll
        for (int i = 0; i < 4; ++i) {
            float4 a = row[i * 64 + lane];
            acc[i] = a.x * qv[i].x + a.y * qv[i].y + a.z * qv[i].z + a.w * qv[i].w;
        }
#pragma unroll
        for (int off = 8; off; off >>= 1) {
#pragma unroll
            for (int i = 0; i < 4; ++i) acc[i] += __shfl_xor(acc[i], off);
        }
        if ((lane & 15) == 0) {
            int g = lane >> 4;
#pragma unroll
            for (int i = 0; i < 4; ++i) {
                sc_l[wave][4 * i + g][tt] = acc[i];
                mnv[i] = fminf(mnv[i], acc[i]);
                mxv[i] = fmaxf(mxv[i], acc[i]);
            }
        }
    }
    __syncthreads();
    int tt2 = lane & 15;
#pragma unroll
    for (int r = 0; r < 4; ++r) {
        int h = r * 4 + (lane >> 4);
        s[(size_t)h * CT + t0 + tt2] = sc_l[wave][h][tt2];
    }
    if (blockIdx.x < 960) {                     // PAST region: per-head min/max
        if ((lane & 15) == 0) {
            int g = lane >> 4;
#pragma unroll
            for (int i = 0; i < 4; ++i) { smn[wave][4 * i + g] = mnv[i]; smx[wave][4 * i + g] = mxv[i]; }
        }
        __syncthreads();
        if (threadIdx.x < 16) {
            int h = threadIdx.x;
            float mn = smn[0][h], mx = smx[0][h];
            for (int w2 = 1; w2 < 4; ++w2) {
                mn = fminf(mn, smn[w2][h]);
                mx = fmaxf(mx, smx[w2][h]);
            }
            atomicMin(&umin[h], desc_key(mx));
            atomicMax(&umax[h], desc_key(mn));
        }
    } else {                                    // window: this block == 1 chunk
        int hh = threadIdx.x >> 4, tt = threadIdx.x & 15;
        long long f = 0;
#pragma unroll
        for (int w2 = 0; w2 < 4; ++w2) f += llrintf(sc_l[w2][hh][tt] * 16777216.f);
#pragma unroll
        for (int off = 32; off; off >>= 1) f += __shfl_xor(f, off);
        if (lane == 0) wred[wave] = f;
        __syncthreads();
        if (threadIdx.x == 0)
            cs_fix[NCOMP + (blockIdx.x - 960)] =
                (ull)(wred[0] + wred[1] + wred[2] + wred[3]);
    }
}

// -------- K3 (mega): per-head {hist -> scan+scatter -> rank} -> attn -> out --
__global__ __launch_bounds__(1024, 2) void k_mega(
        const float* __restrict__ s, const float* __restrict__ vc,
        const unsigned* __restrict__ umin, const unsigned* __restrict__ umax,
        unsigned* __restrict__ hist, unsigned* __restrict__ cnt,
        ull* __restrict__ G, unsigned* __restrict__ stok,
        ull* __restrict__ cs_fix, float* __restrict__ part,
        const float* __restrict__ q, const float* __restrict__ kn,
        const float* __restrict__ vn, const float* __restrict__ Wo,
        float* __restrict__ yg, float* __restrict__ out,
        unsigned* __restrict__ flag) {
    const int bid = blockIdx.x, tid = threadIdx.x;
    const int lane = tid & 63, wave = tid >> 6;
    const int h = bid >> 4, seg = bid & 15;
    __shared__ __align__(16) char smem[40960];
    __shared__ unsigned shT, shN;
    __shared__ unsigned wsum[16];

    float hi, sc; load_params(umin, umax, h, &hi, &sc);
    unsigned* lh = (unsigned*)smem;             // 32 KB: hist, then scan bases

    // ---- Phase C: histogram (16 blocks/head; LDS hist -> device atomicAdd)
    {
        for (int i = tid; i < NB; i += 1024) lh[i] = 0;
        __syncthreads();
        const float* sh = s + (size_t)h * CT + seg * 3840;
        for (int i = tid; i < 3840; i += 1024)
            atomicAdd(&lh[bin_of(sh[i], hi, sc)], 1u);
        __syncthreads();
        unsigned* gh = hist + h * NB;
        for (int i = tid; i < NB; i += 1024) {
            unsigned c = lh[i];
            if (c) atomicAdd(&gh[i], c);
        }
    }
    arrive(flag, 1); wait_head(flag, 1, h);

    // ---- Scan (redundant in every block): lh = exclusive bases; T, ncand
    {
        const unsigned* gh = hist + h * NB;
        unsigned c8[8]; unsigned loc = 0; int b0 = tid * 8;
#pragma unroll
        for (int k = 0; k < 8; ++k) { c8[k] = gh[b0 + k]; loc += c8[k]; }
        unsigned run = loc;
#pragma unroll
        for (int off = 1; off < 64; off <<= 1) {
            unsigned n = __shfl_up(run, off);
            if (lane >= off) run += n;
        }
        if (lane == 63) wsum[wave] = run;
        __syncthreads();
        if (wave == 0 && lane < 16) {
            unsigned v = wsum[lane];
#pragma unroll
            for (int off = 1; off < 16; off <<= 1) {
                unsigned n = __shfl_up(v, off);
                if (lane >= off) v += n;
            }
            wsum[lane] = v;
        }
        __syncthreads();
        unsigned r = run - loc + (wave ? wsum[wave - 1] : 0u);
#pragma unroll
        for (int k = 0; k < 8; ++k) {
            unsigned c = c8[k];
            lh[b0 + k] = r;
            unsigned inc = r + c;
            if (r < KEEP && inc >= KEEP) { shT = (unsigned)(b0 + k); shN = inc; }
            r = inc;
        }
    }
    __syncthreads();
    const unsigned T = shT, ncand = shN;

    // ---- Scatter: static layout pos = lds_base[b] + ticket(cnt)
    {
        const float* sh = s + (size_t)h * CT + seg * 3840;
        unsigned* ch = cnt + h * NB;
        ull* Gh = G + (size_t)h * 65536;
        for (int i = tid; i < 3840; i += 1024) {
            float v = sh[i];
            int b = bin_of(v, hi, sc);
            if ((unsigned)b <= T) {
                unsigned pos = lh[b] + atomicAdd(&ch[b], 1u);
                ST_A(&Gh[pos], ((ull)desc_key(v) << 16) | (unsigned)(seg * 3840 + i));
            }
        }
    }
    arrive(flag, 2); wait_head(flag, 2, h);

    // ---- Phase F: exact rank (static bin bounds from LDS scan)
    {
        ull* csl = (ull*)(smem + 32768);        // 1.5 KB, disjoint from lh
        if (tid < NCOMP) csl[tid] = 0ull;
        __syncthreads();
        const ull* Gh = G + (size_t)h * 65536;
        for (unsigned p = seg * 1024 + tid; p < ncand; p += 16384) {
            ull pk = Gh[p];
            unsigned u = (unsigned)(pk >> 16);
            float v = u_to_f(u);
            int b = bin_of(v, hi, sc);
            unsigned start = lh[b];
            unsigned end = (b == NB - 1) ? ncand : lh[b + 1];
            unsigned rank = start;
            for (unsigned j = start; j < end; ++j) rank += (Gh[j] < pk) ? 1u : 0u;
            if (rank < KEEP) {
                ST_A(&stok[h * KEEP + rank], (unsigned)(pk & 0xFFFFull));
                long long f = llrintf(v * 16777216.f);
                atomicAdd(&csl[rank >> 6], (ull)f);
            }
        }
        __syncthreads();
        if (tid < NCOMP) {
            ull c = csl[tid];
            if (c) atomicAdd(&cs_fix[tid], c);
        }
    }
    arrive(flag, 3); wait_all(flag, 3);

    // ---- Phase H: top-32 (redundant/block) + partial softmax+PV (2 pairs/blk)
    {
        ull* key = (ull*)smem;                       // 2048 B
        unsigned* sel_l = (unsigned*)(smem + 2048);  // 128 B
        float* scm = (float*)(smem + 2176);          // 512 B (2x64)
        float* exb = (float*)(smem + 2688);          // 512 B (2x64)
        float* vbuf = (float*)(smem + 3200);         // 2 x 64 x 68 floats
        if (tid < 256) {
            long long v = (long long)cs_fix[tid];    // plain: first touch post-F
            ull bb = (ull)(v + (1ll << 45));
            key[tid] = (((1ull << 46) - bb) << 8) | (unsigned)tid;
        }
        __syncthreads();
        for (unsigned k = 2; k <= 256; k <<= 1) {
            for (unsigned j = k >> 1; j > 0; j >>= 1) {
                if (tid < 256) {
                    unsigned ixj = tid ^ j;
                    if (ixj > (unsigned)tid) {
                        ull a = key[tid], b = key[ixj];
                        bool up = ((tid & k) == 0);
                        if (up ? (a > b) : (a < b)) { key[tid] = b; key[ixj] = a; }
                    }
                }
                __syncthreads();
            }
        }
        if (tid < NSEL) sel_l[tid] = (unsigned)(key[tid] & 0xFFull);
        __syncthreads();

        int su = tid >> 9, sid = tid & 511;
        int p = bid * 2 + su;                    // 0..511; hh == bid>>4 == h
        int hh = p >> 5, ci = p & 31;
        int c = (int)sel_l[ci];
        int g = sid >> 3, q8 = sid & 7;
        int t = (c < NCOMP) ? (int)stok[hh * KEEP + c * 64 + g]   // plain: first touch
                            : (PAST + (c - NCOMP) * 64 + g);
        if (q8 == 0) scm[su * 64 + g] = s[(size_t)hh * CT + t] * 0.125f;
        __syncthreads();
        float m = -1e30f;
        for (int j = 0; j < 64; ++j) m = fmaxf(m, scm[su * 64 + j]);
        float e = expf(scm[su * 64 + g] - m);
        if (q8 == 0) exb[su * 64 + g] = e;
        const float4* vrow = (const float4*)(vc + (size_t)t * C + hh * HS);
        float4 v0 = vrow[q8 * 2], v1 = vrow[q8 * 2 + 1];
        float* vb = vbuf + su * 4352 + g * 68 + q8 * 8;
        vb[0] = e * v0.x; vb[1] = e * v0.y; vb[2] = e * v0.z; vb[3] = e * v0.w;
        vb[4] = e * v1.x; vb[5] = e * v1.y; vb[6] = e * v1.z; vb[7] = e * v1.w;
        __syncthreads();
        if (sid < 64) {
            float acc = 0.f;
            for (int g2 = 0; g2 < 64; ++g2) acc += vbuf[su * 4352 + g2 * 68 + sid];
            float* P = part + (size_t)(hh * 32 + ci) * 68;
            ST_A(&P[2 + sid], acc);
            if (sid == 0) {
                float es = 0.f;
                for (int g2 = 0; g2 < 64; ++g2) es += exb[su * 64 + g2];
                ST_A(&P[0], m);
                ST_A(&P[1], es);
            }
        }
    }
    arrive(flag, 4); wait_head(flag, 4, h);

    // ---- y[h]: combined once per head (seg 0), 64 lanes
    if (seg == 0 && tid < 64) {
        float p = q[h * 64 + tid] * kn[h * 64 + tid];
#pragma unroll
        for (int off = 32; off; off >>= 1) p += __shfl_xor(p, off);
        float a_new = p * 0.125f;
        const float* P0 = part + (size_t)h * 32 * 68;   // plain: head-local
        float m = a_new;
        for (int ci = 0; ci < 32; ++ci) m = fmaxf(m, P0[ci * 68]);
        float den = expf(a_new - m);
        float acc = den * vn[h * HS + tid];
        for (int ci = 0; ci < 32; ++ci) {
            float w = expf(P0[ci * 68] - m);
            den += w * P0[ci * 68 + 1];
            acc += w * P0[ci * 68 + 2 + tid];
        }
        ST_A(&yg[h * HS + tid], acc / den);
    }
    arrive(flag, 5); wait_all(flag, 5);

    // ---- Wo matmul: block bid -> rows [bid*4, bid*4+4), wave = (row, quarter)
    {
        float* yl = (float*)smem;                 // 4 KB
        float* ps = (float*)(smem + 4096);        // 64 B
        yl[tid] = yg[tid];                        // plain: first touch this block
        __syncthreads();
        int row = bid * 4 + (wave >> 2), qtr = wave & 3;
        const float4* Wrow = (const float4*)(Wo + (size_t)row * C) + qtr * 64;
        const float4* y4 = (const float4*)yl + qtr * 64;
        float4 a = Wrow[lane], b = y4[lane];
        float acc = a.x * b.x + a.y * b.y + a.z * b.z + a.w * b.w;
#pragma unroll
        for (int off = 32; off; off >>= 1) acc += __shfl_xor(acc, off);
        if (lane == 0) ps[wave] = acc;
        __syncthreads();
        if (tid < 4)
            out[bid * 4 + tid] = ps[tid * 4] + ps[tid * 4 + 1] + ps[tid * 4 + 2] + ps[tid * 4 + 3];
    }
}

extern "C" void kernel_launch(void* const* d_in, const int* in_sizes, int n_in,
                              void* d_out, int out_size, void* d_ws, size_t ws_size,
                              hipStream_t stream) {
    const float* x  = (const float*)d_in[0];
    const float* kc = (const float*)d_in[1];
    const float* vc = (const float*)d_in[2];
    const float* Wr = (const float*)d_in[3];
    const float* Wk = (const float*)d_in[4];
    const float* Wv = (const float*)d_in[5];
    const float* Wo = (const float*)d_in[6];
    float* out = (float*)d_out;
    char* ws = (char*)d_ws;

    float* q    = (float*)(ws + 0);
    float* kn   = (float*)(ws + 8192);
    float* vn   = (float*)(ws + 16384);
    ull* cs_fix = (ull*)(ws + 32768);                  // 2 KiB
    float* yg   = (float*)(ws + 40960);                // 4 KiB
    float* part = (float*)(ws + 49152);                // 139264 B
    unsigned* stok = (unsigned*)(ws + 196608);         // 786432 B
    unsigned* umin = (unsigned*)(ws + 1048576);
    unsigned* umax = (unsigned*)(ws + 1048640);
    unsigned* flag = (unsigned*)(ws + 1048832);        // 8 KiB (256 x 32B)
    unsigned* hist = (unsigned*)(ws + 1114112);        // 512 KiB
    unsigned* cnt  = (unsigned*)(ws + 1638400);        // 512 KiB (scatter tickets)
    float* s = (float*)(ws + 2621440);                 // 4 MiB
    ull* G = (ull*)(ws + 7340032);                     // 8 MiB

    k_proj<<<768, 256, 0, stream>>>(x, Wr, Wk, Wv, q, kn, vn, hist, umin, umax, cs_fix, flag);
    k_scores<<<1024, 256, 0, stream>>>(kc, q, s, umin, umax, cs_fix);
    k_mega<<<NBLK, 1024, 0, stream>>>(s, vc, umin, umax, hist, cnt, G, stok, cs_fix,
                                      part, q, kn, vn, Wo, yg, out, flag);
}

// Round 14
// 119.154 us; speedup vs baseline: 1.8478x; 1.0406x over previous
//
#include <hip/hip_runtime.h>
#include <stdint.h>

#define C      1024
#define NH     16
#define HS     64
#define CT     65536
#define PAST   61440   // CT - WINDOW
#define KEEP   12288   // MIN_KV - WINDOW
#define NCOMP  192     // KEEP/64
#define NSEL   32
#define NB     8192    // selection bins
#define NBLK   256     // mega-kernel grid (1 block/CU, co-resident)
#define FLAGW  8       // u32 stride between per-block flags (32 B lines)

typedef unsigned long long ull;

// agent-scope relaxed accessors: write-through / fresh-read at coherence point
#define LD_A(p)   __hip_atomic_load((p), __ATOMIC_RELAXED, __HIP_MEMORY_SCOPE_AGENT)
#define ST_A(p,v) __hip_atomic_store((p), (v), __ATOMIC_RELAXED, __HIP_MEMORY_SCOPE_AGENT)

// monotone transform: larger float => smaller u (asc u == desc value)
__device__ __forceinline__ unsigned int desc_key(float f) {
    unsigned int b = __float_as_uint(f);
    return (b >> 31) ? b : (~b & 0x7FFFFFFFu);
}
__device__ __forceinline__ float u_to_f(unsigned int u) {
    unsigned int b = (u & 0x80000000u) ? u : (0x7FFFFFFFu - u);
    return __uint_as_float(b);
}
// monotone linear bin: s descending <-> bin ascending
__device__ __forceinline__ int bin_of(float s, float hi, float scale) {
    int b = (int)((hi - s) * scale);
    return b < 0 ? 0 : (b > NB - 1 ? NB - 1 : b);
}
__device__ __forceinline__ void load_params(const unsigned* umin, const unsigned* umax,
                                            int h, float* hi, float* sc) {
    float h2 = u_to_f(umin[h]);
    float lo = u_to_f(umax[h]);
    float r = h2 - lo;
    *hi = h2;
    *sc = (r > 0.f) ? (float)(NB - 1) / r : 0.f;
}

// store-based sense barriers (validated R13): arrival = one scoped STORE to the
// block's own padded flag line; wait = parallel polls. Flags monotone 1..6.
// Preceding __syncthreads + vmcnt drain makes the block's scoped stores visible.
__device__ __forceinline__ void arrive(unsigned* flag, unsigned ph) {
    __syncthreads();
    if (threadIdx.x == 0) {
        asm volatile("s_waitcnt vmcnt(0)" ::: "memory");
        ST_A(&flag[blockIdx.x * FLAGW], ph);
    }
}
__device__ __forceinline__ void wait_head(unsigned* flag, unsigned ph, int h) {
    if (threadIdx.x < 16)
        while (LD_A(&flag[(h * 16 + threadIdx.x) * FLAGW]) < ph)
            __builtin_amdgcn_s_sleep(2);
    __syncthreads();
}
__device__ __forceinline__ void wait_all(unsigned* flag, unsigned ph) {
    if (threadIdx.x < 256)
        while (LD_A(&flag[threadIdx.x * FLAGW]) < ph)
            __builtin_amdgcn_s_sleep(2);
    __syncthreads();
}

// ---------------- K1: q/k/v projections + all zero-inits ---------------------
__global__ void k_proj(const float* __restrict__ x, const float* __restrict__ Wr,
                       const float* __restrict__ Wk, const float* __restrict__ Wv,
                       float* __restrict__ q, float* __restrict__ kn, float* __restrict__ vn,
                       unsigned* __restrict__ hc, unsigned* __restrict__ umin,
                       unsigned* __restrict__ umax, ull* __restrict__ cs_fix,
                       unsigned* __restrict__ flag) {
    int gid = blockIdx.x * 256 + threadIdx.x;       // 0..196607
    for (int i = gid; i < 2 * NH * NB; i += 196608) hc[i] = 0;   // hist + cnt
    if (blockIdx.x >= 512 && blockIdx.x < 520)
        flag[(blockIdx.x - 512) * 256 + threadIdx.x] = 0u;       // 2048 u32
    if (blockIdx.x == 700) {
        if (threadIdx.x < 16) umin[threadIdx.x] = 0xFFFFFFFFu;
        else if (threadIdx.x < 32) umax[threadIdx.x - 16] = 0u;
    }
    if (blockIdx.x == 701 && threadIdx.x < 256) cs_fix[threadIdx.x] = 0ull;

    int w = blockIdx.x * (blockDim.x >> 6) + (threadIdx.x >> 6); // 0..3071
    int lane = threadIdx.x & 63;
    int mat = w >> 10, row = w & 1023;
    const float* W = (mat == 0) ? Wr : (mat == 1) ? Wk : Wv;
    const float4* Wrow = (const float4*)(W + (size_t)row * C);
    const float4* x4 = (const float4*)x;
    float acc = 0.f;
#pragma unroll
    for (int i = 0; i < 4; ++i) {
        float4 a = Wrow[i * 64 + lane];
        float4 b = x4[i * 64 + lane];
        acc += a.x * b.x + a.y * b.y + a.z * b.z + a.w * b.w;
    }
#pragma unroll
    for (int off = 32; off; off >>= 1) acc += __shfl_xor(acc, off);
    if (lane == 0) { (mat == 0 ? q : (mat == 1 ? kn : vn))[row] = acc; }
}

// ---- K2 (mega): scores -> {hist -> scan+scatter -> rank}/head -> attn -> out
__global__ __launch_bounds__(1024, 2) void k_mega(
        const float* __restrict__ kc, const float* __restrict__ s_dummy,
        const float* __restrict__ vc,
        unsigned* __restrict__ umin, unsigned* __restrict__ umax,
        unsigned* __restrict__ hist, unsigned* __restrict__ cnt,
        ull* __restrict__ G, unsigned* __restrict__ stok,
        ull* __restrict__ cs_fix, float* __restrict__ part,
        const float* __restrict__ q, const float* __restrict__ kn,
        const float* __restrict__ vn, const float* __restrict__ Wo,
        float* __restrict__ yg, float* __restrict__ out,
        float* __restrict__ s, unsigned* __restrict__ flag) {
    const int bid = blockIdx.x, tid = threadIdx.x;
    const int lane = tid & 63, wave = tid >> 6;
    const int h = bid >> 4, seg = bid & 15;
    __shared__ __align__(16) char smem[49664];
    __shared__ unsigned shT, shN;
    __shared__ unsigned wsum[16];
    __shared__ long long wredl[16];

    // ---- Phase B: scores for tokens [bid*256, bid*256+256); 16/wave ---------
    {
        float (*scl)[16][17] = (float(*)[16][17])smem;        // 18496 B
        float* smn = (float*)(smem + 18496);                  // 1 KB
        float* smx = (float*)(smem + 19520);                  // 1 KB
        const int t0 = bid * 256 + wave * 16;
        const float4* q4 = (const float4*)q;
        float4 qv[4];
#pragma unroll
        for (int i = 0; i < 4; ++i) qv[i] = q4[i * 64 + lane];
        float mnv[4] = {3.4e38f, 3.4e38f, 3.4e38f, 3.4e38f};
        float mxv[4] = {-3.4e38f, -3.4e38f, -3.4e38f, -3.4e38f};
        for (int tt = 0; tt < 16; ++tt) {
            const float4* row = (const float4*)(kc + (size_t)(t0 + tt) * C);
            float acc[4];
#pragma unroll
            for (int i = 0; i < 4; ++i) {
                float4 a = row[i * 64 + lane];
                acc[i] = a.x * qv[i].x + a.y * qv[i].y + a.z * qv[i].z + a.w * qv[i].w;
            }
#pragma unroll
            for (int off = 8; off; off >>= 1) {
#pragma unroll
                for (int i = 0; i < 4; ++i) acc[i] += __shfl_xor(acc[i], off);
            }
            if ((lane & 15) == 0) {
                int g = lane >> 4;
#pragma unroll
                for (int i = 0; i < 4; ++i) {
                    scl[wave][4 * i + g][tt] = acc[i];
                    mnv[i] = fminf(mnv[i], acc[i]);
                    mxv[i] = fmaxf(mxv[i], acc[i]);
                }
            }
        }
        __syncthreads();
        // write: 64B-per-head contiguous lines, scoped (cross-XCD visibility)
        int tt2 = lane & 15;
#pragma unroll
        for (int r = 0; r < 4; ++r) {
            int h2 = r * 4 + (lane >> 4);
            ST_A(&s[(size_t)h2 * CT + t0 + tt2], scl[wave][h2][tt2]);
        }
        if (bid < 240) {                        // PAST region: per-head min/max
            if ((lane & 15) == 0) {
                int g = lane >> 4;
#pragma unroll
                for (int i = 0; i < 4; ++i) {
                    smn[wave * 16 + 4 * i + g] = mnv[i];
                    smx[wave * 16 + 4 * i + g] = mxv[i];
                }
            }
            __syncthreads();
            if (tid < 16) {
                float mn = smn[tid], mx = smx[tid];
                for (int w2 = 1; w2 < 16; ++w2) {
                    mn = fminf(mn, smn[w2 * 16 + tid]);
                    mx = fmaxf(mx, smx[w2 * 16 + tid]);
                }
                atomicMin(&umin[tid], desc_key(mx));
                atomicMax(&umax[tid], desc_key(mn));
            }
        } else {                                // window: 4 chunks per block
            int k = tid >> 8, sub = tid & 255, hh = sub >> 4, tt = sub & 15;
            long long f = 0;
#pragma unroll
            for (int w2 = 0; w2 < 4; ++w2)
                f += llrintf(scl[4 * k + w2][hh][tt] * 16777216.f);
#pragma unroll
            for (int off = 32; off; off >>= 1) f += __shfl_xor(f, off);
            if ((tid & 63) == 0) wredl[wave] = f;
            __syncthreads();
            if ((tid & 255) == 0)
                ST_A(&cs_fix[NCOMP + (bid - 240) * 4 + k],
                     (ull)(wredl[4 * k] + wredl[4 * k + 1] + wredl[4 * k + 2] + wredl[4 * k + 3]));
        }
    }
    arrive(flag, 1); wait_all(flag, 1);

    float hi, sc; load_params(umin, umax, h, &hi, &sc);
    unsigned* lh = (unsigned*)smem;             // 32 KB: hist, then scan bases
    float* s_local = (float*)(smem + 32768);    // 15360 B: this block's s slice

    // ---- Phase C: histogram (16 blocks/head; LDS hist -> device atomicAdd)
    {
        for (int i = tid; i < NB; i += 1024) lh[i] = 0;
        __syncthreads();
        const float* sh = s + (size_t)h * CT + seg * 3840;
        for (int i = tid; i < 3840; i += 1024) {
            float v = sh[i];
            s_local[i] = v;
            atomicAdd(&lh[bin_of(v, hi, sc)], 1u);
        }
        __syncthreads();
        unsigned* gh = hist + h * NB;
        for (int i = tid; i < NB; i += 1024) {
            unsigned c = lh[i];
            if (c) atomicAdd(&gh[i], c);
        }
    }
    arrive(flag, 2); wait_head(flag, 2, h);

    // ---- Scan (redundant in every block): lh = exclusive bases; T, ncand
    {
        const unsigned* gh = hist + h * NB;
        unsigned c8[8]; unsigned loc = 0; int b0 = tid * 8;
#pragma unroll
        for (int k = 0; k < 8; ++k) { c8[k] = gh[b0 + k]; loc += c8[k]; }
        unsigned run = loc;
#pragma unroll
        for (int off = 1; off < 64; off <<= 1) {
            unsigned n = __shfl_up(run, off);
            if (lane >= off) run += n;
        }
        if (lane == 63) wsum[wave] = run;
        __syncthreads();
        if (wave == 0 && lane < 16) {
            unsigned v = wsum[lane];
#pragma unroll
            for (int off = 1; off < 16; off <<= 1) {
                unsigned n = __shfl_up(v, off);
                if (lane >= off) v += n;
            }
            wsum[lane] = v;
        }
        __syncthreads();
        unsigned r = run - loc + (wave ? wsum[wave - 1] : 0u);
#pragma unroll
        for (int k = 0; k < 8; ++k) {
            unsigned c = c8[k];
            lh[b0 + k] = r;
            unsigned inc = r + c;
            if (r < KEEP && inc >= KEEP) { shT = (unsigned)(b0 + k); shN = inc; }
            r = inc;
        }
    }
    __syncthreads();
    const unsigned T = shT, ncand = shN;

    // ---- Scatter from LDS cache: pos = lds_base[b] + ticket(cnt)
    {
        unsigned* ch = cnt + h * NB;
        ull* Gh = G + (size_t)h * 65536;
        for (int i = tid; i < 3840; i += 1024) {
            float v = s_local[i];
            int b = bin_of(v, hi, sc);
            if ((unsigned)b <= T) {
                unsigned pos = lh[b] + atomicAdd(&ch[b], 1u);
                ST_A(&Gh[pos], ((ull)desc_key(v) << 16) | (unsigned)(seg * 3840 + i));
            }
        }
    }
    arrive(flag, 3); wait_head(flag, 3, h);

    // ---- Phase F: exact rank (static bin bounds from LDS scan)
    {
        ull* csl = (ull*)(smem + 48128);        // 1.5 KB, disjoint from lh/s_local
        if (tid < NCOMP) csl[tid] = 0ull;
        __syncthreads();
        const ull* Gh = G + (size_t)h * 65536;
        for (unsigned p = seg * 1024 + tid; p < ncand; p += 16384) {
            ull pk = Gh[p];
            unsigned u = (unsigned)(pk >> 16);
            float v = u_to_f(u);
            int b = bin_of(v, hi, sc);
            unsigned start = lh[b];
            unsigned end = (b == NB - 1) ? ncand : lh[b + 1];
            unsigned rank = start;
            for (unsigned j = start; j < end; ++j) rank += (Gh[j] < pk) ? 1u : 0u;
            if (rank < KEEP) {
                ST_A(&stok[h * KEEP + rank], (unsigned)(pk & 0xFFFFull));
                long long f = llrintf(v * 16777216.f);
                atomicAdd(&csl[rank >> 6], (ull)f);
            }
        }
        __syncthreads();
        if (tid < NCOMP) {
            ull c = csl[tid];
            if (c) atomicAdd(&cs_fix[tid], c);
        }
    }
    arrive(flag, 4); wait_all(flag, 4);

    // ---- Phase H: top-32 (redundant/block) + partial softmax+PV (2 pairs/blk)
    {
        ull* key = (ull*)smem;                       // 2048 B
        unsigned* sel_l = (unsigned*)(smem + 2048);  // 128 B
        float* scm = (float*)(smem + 2176);          // 512 B (2x64)
        float* exb = (float*)(smem + 2688);          // 512 B (2x64)
        float* vbuf = (float*)(smem + 3200);         // 2 x 64 x 68 floats
        if (tid < 256) {
            long long v = (long long)cs_fix[tid];    // plain: first touch post-F
            ull bb = (ull)(v + (1ll << 45));
            key[tid] = (((1ull << 46) - bb) << 8) | (unsigned)tid;
        }
        __syncthreads();
        for (unsigned k = 2; k <= 256; k <<= 1) {
            for (unsigned j = k >> 1; j > 0; j >>= 1) {
                if (tid < 256) {
                    unsigned ixj = tid ^ j;
                    if (ixj > (unsigned)tid) {
                        ull a = key[tid], b = key[ixj];
                        bool up = ((tid & k) == 0);
                        if (up ? (a > b) : (a < b)) { key[tid] = b; key[ixj] = a; }
                    }
                }
                __syncthreads();
            }
        }
        if (tid < NSEL) sel_l[tid] = (unsigned)(key[tid] & 0xFFull);
        __syncthreads();

        int su = tid >> 9, sid = tid & 511;
        int p = bid * 2 + su;                    // 0..511; hh == bid>>4 == h
        int hh = p >> 5, ci = p & 31;
        int c = (int)sel_l[ci];
        int g = sid >> 3, q8 = sid & 7;
        int t = (c < NCOMP) ? (int)stok[hh * KEEP + c * 64 + g]   // plain: first touch
                            : (PAST + (c - NCOMP) * 64 + g);
        if (q8 == 0) scm[su * 64 + g] = s[(size_t)hh * CT + t] * 0.125f;
        __syncthreads();
        float m = -1e30f;
        for (int j = 0; j < 64; ++j) m = fmaxf(m, scm[su * 64 + j]);
        float e = expf(scm[su * 64 + g] - m);
        if (q8 == 0) exb[su * 64 + g] = e;
        const float4* vrow = (const float4*)(vc + (size_t)t * C + hh * HS);
        float4 v0 = vrow[q8 * 2], v1 = vrow[q8 * 2 + 1];
        float* vb = vbuf + su * 4352 + g * 68 + q8 * 8;
        vb[0] = e * v0.x; vb[1] = e * v0.y; vb[2] = e * v0.z; vb[3] = e * v0.w;
        vb[4] = e * v1.x; vb[5] = e * v1.y; vb[6] = e * v1.z; vb[7] = e * v1.w;
        __syncthreads();
        if (sid < 64) {
            float acc = 0.f;
            for (int g2 = 0; g2 < 64; ++g2) acc += vbuf[su * 4352 + g2 * 68 + sid];
            float* P = part + (size_t)(hh * 32 + ci) * 68;
            ST_A(&P[2 + sid], acc);
            if (sid == 0) {
                float es = 0.f;
                for (int g2 = 0; g2 < 64; ++g2) es += exb[su * 64 + g2];
                ST_A(&P[0], m);
                ST_A(&P[1], es);
            }
        }
    }
    arrive(flag, 5); wait_head(flag, 5, h);

    // ---- y[h]: combined once per head (seg 0), 64 lanes
    if (seg == 0 && tid < 64) {
        float p = q[h * 64 + tid] * kn[h * 64 + tid];
#pragma unroll
        for (int off = 32; off; off >>= 1) p += __shfl_xor(p, off);
        float a_new = p * 0.125f;
        const float* P0 = part + (size_t)h * 32 * 68;   // plain: head-local
        float m = a_new;
        for (int ci = 0; ci < 32; ++ci) m = fmaxf(m, P0[ci * 68]);
        float den = expf(a_new - m);
        float acc = den * vn[h * HS + tid];
        for (int ci = 0; ci < 32; ++ci) {
            float w = expf(P0[ci * 68] - m);
            den += w * P0[ci * 68 + 1];
            acc += w * P0[ci * 68 + 2 + tid];
        }
        ST_A(&yg[h * HS + tid], acc / den);
    }
    arrive(flag, 6); wait_all(flag, 6);

    // ---- Wo matmul: block bid -> rows [bid*4, bid*4+4), wave = (row, quarter)
    {
        float* yl = (float*)smem;                 // 4 KB
        float* ps = (float*)(smem + 4096);        // 64 B
        yl[tid] = yg[tid];                        // plain: first touch this block
        __syncthreads();
        int row = bid * 4 + (wave >> 2), qtr = wave & 3;
        const float4* Wrow = (const float4*)(Wo + (size_t)row * C) + qtr * 64;
        const float4* y4 = (const float4*)yl + qtr * 64;
        float4 a = Wrow[lane], b = y4[lane];
        float acc = a.x * b.x + a.y * b.y + a.z * b.z + a.w * b.w;
#pragma unroll
        for (int off = 32; off; off >>= 1) acc += __shfl_xor(acc, off);
        if (lane == 0) ps[wave] = acc;
        __syncthreads();
        if (tid < 4)
            out[bid * 4 + tid] = ps[tid * 4] + ps[tid * 4 + 1] + ps[tid * 4 + 2] + ps[tid * 4 + 3];
    }
}

extern "C" void kernel_launch(void* const* d_in, const int* in_sizes, int n_in,
                              void* d_out, int out_size, void* d_ws, size_t ws_size,
                              hipStream_t stream) {
    const float* x  = (const float*)d_in[0];
    const float* kc = (const float*)d_in[1];
    const float* vc = (const float*)d_in[2];
    const float* Wr = (const float*)d_in[3];
    const float* Wk = (const float*)d_in[4];
    const float* Wv = (const float*)d_in[5];
    const float* Wo = (const float*)d_in[6];
    float* out = (float*)d_out;
    char* ws = (char*)d_ws;

    float* q    = (float*)(ws + 0);
    float* kn   = (float*)(ws + 8192);
    float* vn   = (float*)(ws + 16384);
    ull* cs_fix = (ull*)(ws + 32768);                  // 2 KiB
    float* yg   = (float*)(ws + 40960);                // 4 KiB
    float* part = (float*)(ws + 49152);                // 139264 B
    unsigned* stok = (unsigned*)(ws + 196608);         // 786432 B
    unsigned* umin = (unsigned*)(ws + 1048576);
    unsigned* umax = (unsigned*)(ws + 1048640);
    unsigned* flag = (unsigned*)(ws + 1048832);        // 8 KiB (256 x 32B)
    unsigned* hist = (unsigned*)(ws + 1114112);        // 512 KiB
    unsigned* cnt  = (unsigned*)(ws + 1638400);        // 512 KiB (scatter tickets)
    float* s = (float*)(ws + 2621440);                 // 4 MiB
    ull* G = (ull*)(ws + 7340032);                     // 8 MiB

    k_proj<<<768, 256, 0, stream>>>(x, Wr, Wk, Wv, q, kn, vn, hist, umin, umax, cs_fix, flag);
    k_mega<<<NBLK, 1024, 0, stream>>>(kc, s, vc, umin, umax, hist, cnt, G, stok, cs_fix,
                                      part, q, kn, vn, Wo, yg, out, s, flag);
}

// Round 15
// 117.011 us; speedup vs baseline: 1.8816x; 1.0183x over previous
//
#include <hip/hip_runtime.h>
#include <stdint.h>

#define C      1024
#define NH     16
#define HS     64
#define CT     65536
#define PAST   61440   // CT - WINDOW
#define KEEP   12288   // MIN_KV - WINDOW
#define NCOMP  192     // KEEP/64
#define NSEL   32
#define NB     8192    // selection bins
#define NBLK   256     // mega-kernel grid (1 block/CU, co-resident)
#define FLAGW  8       // u32 stride between per-block flags (32 B lines)

typedef unsigned long long ull;

// agent-scope relaxed accessors: write-through / fresh-read at coherence point
#define LD_A(p)   __hip_atomic_load((p), __ATOMIC_RELAXED, __HIP_MEMORY_SCOPE_AGENT)
#define ST_A(p,v) __hip_atomic_store((p), (v), __ATOMIC_RELAXED, __HIP_MEMORY_SCOPE_AGENT)

// monotone transform: larger float => smaller u (asc u == desc value)
__device__ __forceinline__ unsigned int desc_key(float f) {
    unsigned int b = __float_as_uint(f);
    return (b >> 31) ? b : (~b & 0x7FFFFFFFu);
}
__device__ __forceinline__ float u_to_f(unsigned int u) {
    unsigned int b = (u & 0x80000000u) ? u : (0x7FFFFFFFu - u);
    return __uint_as_float(b);
}
// monotone linear bin: s descending <-> bin ascending
__device__ __forceinline__ int bin_of(float s, float hi, float scale) {
    int b = (int)((hi - s) * scale);
    return b < 0 ? 0 : (b > NB - 1 ? NB - 1 : b);
}
__device__ __forceinline__ void load_params(const unsigned* umin, const unsigned* umax,
                                            int h, float* hi, float* sc) {
    float h2 = u_to_f(umin[h]);
    float lo = u_to_f(umax[h]);
    float r = h2 - lo;
    *hi = h2;
    *sc = (r > 0.f) ? (float)(NB - 1) / r : 0.f;
}

// store-based sense barriers (validated R13/R14): arrival = one scoped STORE to
// the block's own padded flag line; wait = parallel polls. Flags monotone 1..6.
__device__ __forceinline__ void arrive(unsigned* flag, unsigned ph) {
    __syncthreads();
    if (threadIdx.x == 0) {
        asm volatile("s_waitcnt vmcnt(0)" ::: "memory");
        ST_A(&flag[blockIdx.x * FLAGW], ph);
    }
}
__device__ __forceinline__ void wait_head(unsigned* flag, unsigned ph, int h) {
    if (threadIdx.x < 16)
        while (LD_A(&flag[(h * 16 + threadIdx.x) * FLAGW]) < ph)
            __builtin_amdgcn_s_sleep(2);
    __syncthreads();
}
__device__ __forceinline__ void wait_all(unsigned* flag, unsigned ph) {
    if (threadIdx.x < 256)
        while (LD_A(&flag[threadIdx.x * FLAGW]) < ph)
            __builtin_amdgcn_s_sleep(2);
    __syncthreads();
}

// ---------------- K1: q/k/v projections + all zero-inits ---------------------
__global__ void k_proj(const float* __restrict__ x, const float* __restrict__ Wr,
                       const float* __restrict__ Wk, const float* __restrict__ Wv,
                       float* __restrict__ q, float* __restrict__ kn, float* __restrict__ vn,
                       unsigned* __restrict__ hc, unsigned* __restrict__ umin,
                       unsigned* __restrict__ umax, ull* __restrict__ cs_fix,
                       unsigned* __restrict__ flag) {
    int gid = blockIdx.x * 256 + threadIdx.x;       // 0..196607
    for (int i = gid; i < 2 * NH * NB; i += 196608) hc[i] = 0;   // hist + cnt
    if (blockIdx.x >= 512 && blockIdx.x < 520)
        flag[(blockIdx.x - 512) * 256 + threadIdx.x] = 0u;       // 2048 u32
    if (blockIdx.x == 700) {
        if (threadIdx.x < 16) umin[threadIdx.x] = 0xFFFFFFFFu;
        else if (threadIdx.x < 32) umax[threadIdx.x - 16] = 0u;
    }
    if (blockIdx.x == 701 && threadIdx.x < 256) cs_fix[threadIdx.x] = 0ull;

    int w = blockIdx.x * (blockDim.x >> 6) + (threadIdx.x >> 6); // 0..3071
    int lane = threadIdx.x & 63;
    int mat = w >> 10, row = w & 1023;
    const float* W = (mat == 0) ? Wr : (mat == 1) ? Wk : Wv;
    const float4* Wrow = (const float4*)(W + (size_t)row * C);
    const float4* x4 = (const float4*)x;
    float acc = 0.f;
#pragma unroll
    for (int i = 0; i < 4; ++i) {
        float4 a = Wrow[i * 64 + lane];
        float4 b = x4[i * 64 + lane];
        acc += a.x * b.x + a.y * b.y + a.z * b.z + a.w * b.w;
    }
#pragma unroll
    for (int off = 32; off; off >>= 1) acc += __shfl_xor(acc, off);
    if (lane == 0) { (mat == 0 ? q : (mat == 1 ? kn : vn))[row] = acc; }
}

// ---- K2 (mega): scores -> {hist -> scan+scatter -> rank}/head -> attn -> out
__global__ __launch_bounds__(1024, 2) void k_mega(
        const float* __restrict__ kc, const float* __restrict__ vc,
        unsigned* __restrict__ umin, unsigned* __restrict__ umax,
        unsigned* __restrict__ hist, unsigned* __restrict__ cnt,
        ull* __restrict__ G, unsigned* __restrict__ stok,
        ull* __restrict__ cs_fix, float* __restrict__ part,
        const float* __restrict__ q, const float* __restrict__ kn,
        const float* __restrict__ vn, const float* __restrict__ Wo,
        float* __restrict__ yg, float* __restrict__ out,
        float* __restrict__ s, unsigned* __restrict__ flag) {
    const int bid = blockIdx.x, tid = threadIdx.x;
    const int lane = tid & 63, wave = tid >> 6;
    const int h = bid >> 4, seg = bid & 15;
    __shared__ __align__(16) char smem[49664];
    __shared__ unsigned shT, shN;
    __shared__ unsigned wsum[16];
    __shared__ long long wredl[16];

    // ---- Phase B: scores for tokens [bid*256, bid*256+256); 16/wave ---------
    {
        float (*scl)[16][17] = (float(*)[16][17])smem;        // 18496 B
        float* smn = (float*)(smem + 18496);                  // 1 KB
        float* smx = (float*)(smem + 19520);                  // 1 KB
        const int t0 = bid * 256 + wave * 16;
        const float4* q4 = (const float4*)q;
        float4 qv[4];
#pragma unroll
        for (int i = 0; i < 4; ++i) qv[i] = q4[i * 64 + lane];
        float mnv[4] = {3.4e38f, 3.4e38f, 3.4e38f, 3.4e38f};
        float mxv[4] = {-3.4e38f, -3.4e38f, -3.4e38f, -3.4e38f};
        for (int tb = 0; tb < 16; tb += 4) {
            float4 av[4][4];                   // 16 loads in flight per wave
#pragma unroll
            for (int u = 0; u < 4; ++u) {
                const float4* row = (const float4*)(kc + (size_t)(t0 + tb + u) * C);
#pragma unroll
                for (int i = 0; i < 4; ++i) av[u][i] = row[i * 64 + lane];
            }
#pragma unroll
            for (int u = 0; u < 4; ++u) {
                float acc[4];
#pragma unroll
                for (int i = 0; i < 4; ++i)
                    acc[i] = av[u][i].x * qv[i].x + av[u][i].y * qv[i].y
                           + av[u][i].z * qv[i].z + av[u][i].w * qv[i].w;
#pragma unroll
                for (int off = 8; off; off >>= 1) {
#pragma unroll
                    for (int i = 0; i < 4; ++i) acc[i] += __shfl_xor(acc[i], off);
                }
                if ((lane & 15) == 0) {
                    int g = lane >> 4;
#pragma unroll
                    for (int i = 0; i < 4; ++i) {
                        scl[wave][4 * i + g][tb + u] = acc[i];
                        mnv[i] = fminf(mnv[i], acc[i]);
                        mxv[i] = fmaxf(mxv[i], acc[i]);
                    }
                }
            }
        }
        __syncthreads();
        // write: 64B-per-head contiguous lines, scoped (cross-XCD visibility)
        int tt2 = lane & 15;
#pragma unroll
        for (int r = 0; r < 4; ++r) {
            int h2 = r * 4 + (lane >> 4);
            ST_A(&s[(size_t)h2 * CT + t0 + tt2], scl[wave][h2][tt2]);
        }
        if (bid < 240) {                        // PAST region: per-head min/max
            if ((lane & 15) == 0) {
                int g = lane >> 4;
#pragma unroll
                for (int i = 0; i < 4; ++i) {
                    smn[wave * 16 + 4 * i + g] = mnv[i];
                    smx[wave * 16 + 4 * i + g] = mxv[i];
                }
            }
            __syncthreads();
            if (tid < 16) {
                float mn = smn[tid], mx = smx[tid];
                for (int w2 = 1; w2 < 16; ++w2) {
                    mn = fminf(mn, smn[w2 * 16 + tid]);
                    mx = fmaxf(mx, smx[w2 * 16 + tid]);
                }
                atomicMin(&umin[tid], desc_key(mx));
                atomicMax(&umax[tid], desc_key(mn));
            }
        } else {                                // window: 4 chunks per block
            int k = tid >> 8, sub = tid & 255, hh = sub >> 4, tt = sub & 15;
            long long f = 0;
#pragma unroll
            for (int w2 = 0; w2 < 4; ++w2)
                f += llrintf(scl[4 * k + w2][hh][tt] * 16777216.f);
#pragma unroll
            for (int off = 32; off; off >>= 1) f += __shfl_xor(f, off);
            if ((tid & 63) == 0) wredl[wave] = f;
            __syncthreads();
            if ((tid & 255) == 0)
                ST_A(&cs_fix[NCOMP + (bid - 240) * 4 + k],
                     (ull)(wredl[4 * k] + wredl[4 * k + 1] + wredl[4 * k + 2] + wredl[4 * k + 3]));
        }
    }
    arrive(flag, 1); wait_all(flag, 1);

    float hi, sc; load_params(umin, umax, h, &hi, &sc);
    unsigned* lh = (unsigned*)smem;             // 32 KB: hist, then scan bases
    float* s_local = (float*)(smem + 32768);    // 15360 B: this block's s slice

    // ---- Phase C: histogram (16 blocks/head; LDS hist -> device atomicAdd)
    {
        for (int i = tid; i < NB; i += 1024) lh[i] = 0;
        __syncthreads();
        const float* sh = s + (size_t)h * CT + seg * 3840;
        for (int i = tid; i < 3840; i += 1024) {
            float v = sh[i];
            s_local[i] = v;
            atomicAdd(&lh[bin_of(v, hi, sc)], 1u);
        }
        __syncthreads();
        unsigned* gh = hist + h * NB;
        for (int i = tid; i < NB; i += 1024) {
            unsigned c = lh[i];
            if (c) atomicAdd(&gh[i], c);
        }
    }
    arrive(flag, 2); wait_head(flag, 2, h);

    // ---- Scan (redundant in every block): lh = exclusive bases; T, ncand
    {
        const unsigned* gh = hist + h * NB;
        unsigned c8[8]; unsigned loc = 0; int b0 = tid * 8;
#pragma unroll
        for (int k = 0; k < 8; ++k) { c8[k] = gh[b0 + k]; loc += c8[k]; }
        unsigned run = loc;
#pragma unroll
        for (int off = 1; off < 64; off <<= 1) {
            unsigned n = __shfl_up(run, off);
            if (lane >= off) run += n;
        }
        if (lane == 63) wsum[wave] = run;
        __syncthreads();
        if (wave == 0 && lane < 16) {
            unsigned v = wsum[lane];
#pragma unroll
            for (int off = 1; off < 16; off <<= 1) {
                unsigned n = __shfl_up(v, off);
                if (lane >= off) v += n;
            }
            wsum[lane] = v;
        }
        __syncthreads();
        unsigned r = run - loc + (wave ? wsum[wave - 1] : 0u);
#pragma unroll
        for (int k = 0; k < 8; ++k) {
            unsigned c = c8[k];
            lh[b0 + k] = r;
            unsigned inc = r + c;
            if (r < KEEP && inc >= KEEP) { shT = (unsigned)(b0 + k); shN = inc; }
            r = inc;
        }
    }
    __syncthreads();
    const unsigned T = shT, ncand = shN;

    // ---- Scatter from LDS cache: pos = lds_base[b] + ticket(cnt)
    {
        unsigned* ch = cnt + h * NB;
        ull* Gh = G + (size_t)h * 65536;
        for (int i = tid; i < 3840; i += 1024) {
            float v = s_local[i];
            int b = bin_of(v, hi, sc);
            if ((unsigned)b <= T) {
                unsigned pos = lh[b] + atomicAdd(&ch[b], 1u);
                ST_A(&Gh[pos], ((ull)desc_key(v) << 16) | (unsigned)(seg * 3840 + i));
            }
        }
    }
    arrive(flag, 3); wait_head(flag, 3, h);

    // ---- Phase F: exact rank (static bin bounds from LDS scan)
    {
        ull* csl = (ull*)(smem + 48128);        // 1.5 KB, disjoint from lh/s_local
        if (tid < NCOMP) csl[tid] = 0ull;
        __syncthreads();
        const ull* Gh = G + (size_t)h * 65536;
        for (unsigned p = seg * 1024 + tid; p < ncand; p += 16384) {
            ull pk = Gh[p];
            unsigned u = (unsigned)(pk >> 16);
            float v = u_to_f(u);
            int b = bin_of(v, hi, sc);
            unsigned start = lh[b];
            unsigned end = (b == NB - 1) ? ncand : lh[b + 1];
            unsigned rank = start;
            for (unsigned j = start; j < end; ++j) rank += (Gh[j] < pk) ? 1u : 0u;
            if (rank < KEEP) {
                ST_A(&stok[h * KEEP + rank], (unsigned)(pk & 0xFFFFull));
                long long f = llrintf(v * 16777216.f);
                atomicAdd(&csl[rank >> 6], (ull)f);
            }
        }
        __syncthreads();
        if (tid < NCOMP) {
            ull c = csl[tid];
            if (c) atomicAdd(&cs_fix[tid], c);
        }
    }
    arrive(flag, 4); wait_all(flag, 4);

    // ---- Phase H: top-32 (redundant/block) + partial softmax+PV (2 pairs/blk)
    {
        ull* key = (ull*)smem;                       // 2048 B
        unsigned* sel_l = (unsigned*)(smem + 2048);  // 128 B
        float* scm = (float*)(smem + 2176);          // 512 B (2x64)
        float* exb = (float*)(smem + 2688);          // 512 B (2x64)
        float* vbuf = (float*)(smem + 3200);         // 2 x 64 x 68 floats
        if (tid < 256) {
            long long v = (long long)cs_fix[tid];    // plain: first touch post-F
            ull bb = (ull)(v + (1ll << 45));
            key[tid] = (((1ull << 46) - bb) << 8) | (unsigned)tid;
        }
        __syncthreads();
        for (unsigned k = 2; k <= 256; k <<= 1) {
            for (unsigned j = k >> 1; j > 0; j >>= 1) {
                if (tid < 256) {
                    unsigned ixj = tid ^ j;
                    if (ixj > (unsigned)tid) {
                        ull a = key[tid], b = key[ixj];
                        bool up = ((tid & k) == 0);
                        if (up ? (a > b) : (a < b)) { key[tid] = b; key[ixj] = a; }
                    }
                }
                __syncthreads();
            }
        }
        if (tid < NSEL) sel_l[tid] = (unsigned)(key[tid] & 0xFFull);
        __syncthreads();

        int su = tid >> 9, sid = tid & 511;
        int p = bid * 2 + su;                    // 0..511; hh == bid>>4 == h
        int hh = p >> 5, ci = p & 31;
        int c = (int)sel_l[ci];
        int g = sid >> 3, q8 = sid & 7;
        int t = (c < NCOMP) ? (int)stok[hh * KEEP + c * 64 + g]   // plain: first touch
                            : (PAST + (c - NCOMP) * 64 + g);
        if (q8 == 0) scm[su * 64 + g] = s[(size_t)hh * CT + t] * 0.125f;
        __syncthreads();
        float m = -1e30f;
        for (int j = 0; j < 64; ++j) m = fmaxf(m, scm[su * 64 + j]);
        float e = expf(scm[su * 64 + g] - m);
        if (q8 == 0) exb[su * 64 + g] = e;
        const float4* vrow = (const float4*)(vc + (size_t)t * C + hh * HS);
        float4 v0 = vrow[q8 * 2], v1 = vrow[q8 * 2 + 1];
        float* vb = vbuf + su * 4352 + g * 68 + q8 * 8;
        vb[0] = e * v0.x; vb[1] = e * v0.y; vb[2] = e * v0.z; vb[3] = e * v0.w;
        vb[4] = e * v1.x; vb[5] = e * v1.y; vb[6] = e * v1.z; vb[7] = e * v1.w;
        __syncthreads();
        if (sid < 64) {
            float acc = 0.f;
            for (int g2 = 0; g2 < 64; ++g2) acc += vbuf[su * 4352 + g2 * 68 + sid];
            float* P = part + (size_t)(hh * 32 + ci) * 68;
            ST_A(&P[2 + sid], acc);
            if (sid == 0) {
                float es = 0.f;
                for (int g2 = 0; g2 < 64; ++g2) es += exb[su * 64 + g2];
                ST_A(&P[0], m);
                ST_A(&P[1], es);
            }
        }
    }
    arrive(flag, 5); wait_head(flag, 5, h);

    // ---- Wo prefetch (independent of y) hides under the y barrier
    int row = bid * 4 + (wave >> 2), qtr = wave & 3;
    const float4* Wrow4 = (const float4*)(Wo + (size_t)row * C) + qtr * 64;
    float4 wa = Wrow4[lane];

    // ---- y[h]: combined once per head (seg 0), 64 lanes
    if (seg == 0 && tid < 64) {
        float p = q[h * 64 + tid] * kn[h * 64 + tid];
#pragma unroll
        for (int off = 32; off; off >>= 1) p += __shfl_xor(p, off);
        float a_new = p * 0.125f;
        const float* P0 = part + (size_t)h * 32 * 68;   // plain: head-local
        float m = a_new;
        for (int ci = 0; ci < 32; ++ci) m = fmaxf(m, P0[ci * 68]);
        float den = expf(a_new - m);
        float acc = den * vn[h * HS + tid];
        for (int ci = 0; ci < 32; ++ci) {
            float w = expf(P0[ci * 68] - m);
            den += w * P0[ci * 68 + 1];
            acc += w * P0[ci * 68 + 2 + tid];
        }
        ST_A(&yg[h * HS + tid], acc / den);
    }
    if (seg == 0) arrive(flag, 6);             // only y-writers publish phase 6
    // wait on the 16 y-writer flags only
    if (tid < 16)
        while (LD_A(&flag[(tid * 16) * FLAGW]) < 6u) __builtin_amdgcn_s_sleep(2);
    __syncthreads();

    // ---- Wo matmul: block bid -> rows [bid*4, bid*4+4), wave = (row, quarter)
    {
        float* yl = (float*)smem;                 // 4 KB
        float* ps = (float*)(smem + 4096);        // 64 B
        yl[tid] = yg[tid];                        // plain: first touch this block
        __syncthreads();
        const float4* y4 = (const float4*)yl + qtr * 64;
        float4 b = y4[lane];
        float acc = wa.x * b.x + wa.y * b.y + wa.z * b.z + wa.w * b.w;
#pragma unroll
        for (int off = 32; off; off >>= 1) acc += __shfl_xor(acc, off);
        if (lane == 0) ps[wave] = acc;
        __syncthreads();
        if (tid < 4)
            out[bid * 4 + tid] = ps[tid * 4] + ps[tid * 4 + 1] + ps[tid * 4 + 2] + ps[tid * 4 + 3];
    }
}

extern "C" void kernel_launch(void* const* d_in, const int* in_sizes, int n_in,
                              void* d_out, int out_size, void* d_ws, size_t ws_size,
                              hipStream_t stream) {
    const float* x  = (const float*)d_in[0];
    const float* kc = (const float*)d_in[1];
    const float* vc = (const float*)d_in[2];
    const float* Wr = (const float*)d_in[3];
    const float* Wk = (const float*)d_in[4];
    const float* Wv = (const float*)d_in[5];
    const float* Wo = (const float*)d_in[6];
    float* out = (float*)d_out;
    char* ws = (char*)d_ws;

    float* q    = (float*)(ws + 0);
    float* kn   = (float*)(ws + 8192);
    float* vn   = (float*)(ws + 16384);
    ull* cs_fix = (ull*)(ws + 32768);                  // 2 KiB
    float* yg   = (float*)(ws + 40960);                // 4 KiB
    float* part = (float*)(ws + 49152);                // 139264 B
    unsigned* stok = (unsigned*)(ws + 196608);         // 786432 B
    unsigned* umin = (unsigned*)(ws + 1048576);
    unsigned* umax = (unsigned*)(ws + 1048640);
    unsigned* flag = (unsigned*)(ws + 1048832);        // 8 KiB (256 x 32B)
    unsigned* hist = (unsigned*)(ws + 1114112);        // 512 KiB
    unsigned* cnt  = (unsigned*)(ws + 1638400);        // 512 KiB (scatter tickets)
    float* s = (float*)(ws + 2621440);                 // 4 MiB
    ull* G = (ull*)(ws + 7340032);                     // 8 MiB

    k_proj<<<768, 256, 0, stream>>>(x, Wr, Wk, Wv, q, kn, vn, hist, umin, umax, cs_fix, flag);
    k_mega<<<NBLK, 1024, 0, stream>>>(kc, vc, umin, umax, hist, cnt, G, stok, cs_fix,
                                      part, q, kn, vn, Wo, yg, out, s, flag);
}

// Round 16
// 115.496 us; speedup vs baseline: 1.9063x; 1.0131x over previous
//
#include <hip/hip_runtime.h>
#include <stdint.h>

#define C      1024
#define NH     16
#define HS     64
#define CT     65536
#define PAST   61440   // CT - WINDOW
#define KEEP   12288   // MIN_KV - WINDOW
#define NCOMP  192     // KEEP/64
#define NSEL   32
#define NB     8192    // selection bins
#define NBLK   256     // mega-kernel grid (1 block/CU, co-resident)
#define FLAGW  8       // u32 stride between per-block flags (32 B lines)

typedef unsigned long long ull;

// agent-scope relaxed accessors: write-through / fresh-read at coherence point
#define LD_A(p)   __hip_atomic_load((p), __ATOMIC_RELAXED, __HIP_MEMORY_SCOPE_AGENT)
#define ST_A(p,v) __hip_atomic_store((p), (v), __ATOMIC_RELAXED, __HIP_MEMORY_SCOPE_AGENT)

// monotone transform: larger float => smaller u (asc u == desc value)
__device__ __forceinline__ unsigned int desc_key(float f) {
    unsigned int b = __float_as_uint(f);
    return (b >> 31) ? b : (~b & 0x7FFFFFFFu);
}
__device__ __forceinline__ float u_to_f(unsigned int u) {
    unsigned int b = (u & 0x80000000u) ? u : (0x7FFFFFFFu - u);
    return __uint_as_float(b);
}
// monotone linear bin: s descending <-> bin ascending
__device__ __forceinline__ int bin_of(float s, float hi, float scale) {
    int b = (int)((hi - s) * scale);
    return b < 0 ? 0 : (b > NB - 1 ? NB - 1 : b);
}
__device__ __forceinline__ void load_params(const unsigned* umin, const unsigned* umax,
                                            int h, float* hi, float* sc) {
    float h2 = u_to_f(umin[h]);
    float lo = u_to_f(umax[h]);
    float r = h2 - lo;
    *hi = h2;
    *sc = (r > 0.f) ? (float)(NB - 1) / r : 0.f;
}

// store-based sense barriers (validated R13-R15): arrival = one scoped STORE to
// the block's own padded flag line; wait = parallel polls. Flags monotone 1..6.
__device__ __forceinline__ void arrive(unsigned* flag, unsigned ph) {
    __syncthreads();
    if (threadIdx.x == 0) {
        asm volatile("s_waitcnt vmcnt(0)" ::: "memory");
        ST_A(&flag[blockIdx.x * FLAGW], ph);
    }
}
__device__ __forceinline__ void wait_head(unsigned* flag, unsigned ph, int h) {
    if (threadIdx.x < 16)
        while (LD_A(&flag[(h * 16 + threadIdx.x) * FLAGW]) < ph)
            __builtin_amdgcn_s_sleep(2);
    __syncthreads();
}
__device__ __forceinline__ void wait_all(unsigned* flag, unsigned ph) {
    if (threadIdx.x < 256)
        while (LD_A(&flag[threadIdx.x * FLAGW]) < ph)
            __builtin_amdgcn_s_sleep(2);
    __syncthreads();
}

// ---------------- K1: q/k/v projections + all zero-inits ---------------------
__global__ void k_proj(const float* __restrict__ x, const float* __restrict__ Wr,
                       const float* __restrict__ Wk, const float* __restrict__ Wv,
                       float* __restrict__ q, float* __restrict__ kn, float* __restrict__ vn,
                       unsigned* __restrict__ hc, unsigned* __restrict__ umin,
                       unsigned* __restrict__ umax, ull* __restrict__ cs_fix,
                       unsigned* __restrict__ flag) {
    int gid = blockIdx.x * 256 + threadIdx.x;       // 0..196607
    for (int i = gid; i < 2 * NH * NB; i += 196608) hc[i] = 0;   // hist + cnt
    if (blockIdx.x >= 512 && blockIdx.x < 520)
        flag[(blockIdx.x - 512) * 256 + threadIdx.x] = 0u;       // 2048 u32
    if (blockIdx.x == 700) {
        if (threadIdx.x < 16) umin[threadIdx.x] = 0xFFFFFFFFu;
        else if (threadIdx.x < 32) umax[threadIdx.x - 16] = 0u;
    }
    if (blockIdx.x == 701 && threadIdx.x < 256) cs_fix[threadIdx.x] = 0ull;

    int w = blockIdx.x * (blockDim.x >> 6) + (threadIdx.x >> 6); // 0..3071
    int lane = threadIdx.x & 63;
    int mat = w >> 10, row = w & 1023;
    const float* W = (mat == 0) ? Wr : (mat == 1) ? Wk : Wv;
    const float4* Wrow = (const float4*)(W + (size_t)row * C);
    const float4* x4 = (const float4*)x;
    float acc = 0.f;
#pragma unroll
    for (int i = 0; i < 4; ++i) {
        float4 a = Wrow[i * 64 + lane];
        float4 b = x4[i * 64 + lane];
        acc += a.x * b.x + a.y * b.y + a.z * b.z + a.w * b.w;
    }
#pragma unroll
    for (int off = 32; off; off >>= 1) acc += __shfl_xor(acc, off);
    if (lane == 0) { (mat == 0 ? q : (mat == 1 ? kn : vn))[row] = acc; }
}

// ---- K2 (mega): per-head scores -> hist -> scan+scatter -> rank -> attn -> out
__global__ __launch_bounds__(1024, 2) void k_mega(
        const float* __restrict__ kc, const float* __restrict__ vc,
        unsigned* __restrict__ umin, unsigned* __restrict__ umax,
        unsigned* __restrict__ hist, unsigned* __restrict__ cnt,
        ull* __restrict__ G, ull* __restrict__ stokv,
        ull* __restrict__ cs_fix, float* __restrict__ part,
        const float* __restrict__ q, const float* __restrict__ kn,
        const float* __restrict__ vn, const float* __restrict__ Wo,
        float* __restrict__ yg, float* __restrict__ out,
        float* __restrict__ s_win, unsigned* __restrict__ flag) {
    const int bid = blockIdx.x, tid = threadIdx.x;
    const int lane = tid & 63, wave = tid >> 6;
    const int h = bid >> 4, seg = bid & 15;
    __shared__ __align__(16) char smem[50688];
    __shared__ unsigned shT, shN;
    __shared__ unsigned wsum[16];
    __shared__ float smn[16], smx[16];

    float* s_lds = (float*)smem;                // 16 KB: this block's 4096 scores
    unsigned* lh = (unsigned*)(smem + 16384);   // 32 KB: hist, then scan bases

    // ---- Phase B: scores s[h][seg*4096 + i] for i in [0,4096); own head only
    {
        const int t_base = seg * 4096;
        const int g = lane >> 4;                 // 16-lane group 0..3
        float4 qv = ((const float4*)q)[h * 16 + (lane & 15)];
        float mn = 3.4e38f, mx = -3.4e38f;
        for (int ib = 0; ib < 64; ib += 4) {     // 4-token-batch x 4 groups
            float4 av[4];
#pragma unroll
            for (int u = 0; u < 4; ++u) {
                int lt = wave * 256 + (ib + u) * 4 + g;
                av[u] = ((const float4*)(kc + (size_t)(t_base + lt) * C + h * HS))[lane & 15];
            }
#pragma unroll
            for (int u = 0; u < 4; ++u) {
                float d = av[u].x * qv.x + av[u].y * qv.y + av[u].z * qv.z + av[u].w * qv.w;
#pragma unroll
                for (int off = 8; off; off >>= 1) d += __shfl_xor(d, off);
                int lt = wave * 256 + (ib + u) * 4 + g;
                if ((lane & 15) == 0) s_lds[lt] = d;
                mn = fminf(mn, d);
                mx = fmaxf(mx, d);
            }
        }
        __syncthreads();
        if (seg < 15) {                          // PAST: per-head min/max
#pragma unroll
            for (int off = 32; off; off >>= 1) {
                mn = fminf(mn, __shfl_xor(mn, off));
                mx = fmaxf(mx, __shfl_xor(mx, off));
            }
            if (lane == 0) { smn[wave] = mn; smx[wave] = mx; }
            __syncthreads();
            if (tid == 0) {
                float bmn = smn[0], bmx = smx[0];
                for (int w2 = 1; w2 < 16; ++w2) {
                    bmn = fminf(bmn, smn[w2]);
                    bmx = fmaxf(bmx, smx[w2]);
                }
                atomicMin(&umin[h], desc_key(bmx));
                atomicMax(&umax[h], desc_key(bmn));
            }
        } else {                                 // window: s_win + chunk sums
            for (int i = tid; i < 4096; i += 1024)
                ST_A(&s_win[h * 4096 + i], s_lds[i]);
            int c = tid >> 4;                    // 64 chunks x 16 threads
            long long f = 0;
#pragma unroll
            for (int j = 0; j < 4; ++j)
                f += llrintf(s_lds[c * 64 + (tid & 15) * 4 + j] * 16777216.f);
#pragma unroll
            for (int off = 8; off; off >>= 1) f += __shfl_xor(f, off);
            if ((tid & 15) == 0) atomicAdd(&cs_fix[NCOMP + c], (ull)f);
        }
    }
    arrive(flag, 1); wait_head(flag, 1, h);

    float hi, sc; load_params(umin, umax, h, &hi, &sc);

    // ---- Phase C: histogram (segs 0-14; LDS hist -> device atomicAdd)
    {
        for (int i = tid; i < NB; i += 1024) lh[i] = 0;
        __syncthreads();
        if (seg < 15) {
            for (int i = tid; i < 4096; i += 1024)
                atomicAdd(&lh[bin_of(s_lds[i], hi, sc)], 1u);
            __syncthreads();
            unsigned* gh = hist + h * NB;
            for (int i = tid; i < NB; i += 1024) {
                unsigned c = lh[i];
                if (c) atomicAdd(&gh[i], c);
            }
        }
    }
    arrive(flag, 2); wait_head(flag, 2, h);

    // ---- Scan (redundant in every block): lh = exclusive bases; T, ncand
    {
        const unsigned* gh = hist + h * NB;
        unsigned c8[8]; unsigned loc = 0; int b0 = tid * 8;
#pragma unroll
        for (int k = 0; k < 8; ++k) { c8[k] = gh[b0 + k]; loc += c8[k]; }
        unsigned run = loc;
#pragma unroll
        for (int off = 1; off < 64; off <<= 1) {
            unsigned n = __shfl_up(run, off);
            if (lane >= off) run += n;
        }
        if (lane == 63) wsum[wave] = run;
        __syncthreads();
        if (wave == 0 && lane < 16) {
            unsigned v = wsum[lane];
#pragma unroll
            for (int off = 1; off < 16; off <<= 1) {
                unsigned n = __shfl_up(v, off);
                if (lane >= off) v += n;
            }
            wsum[lane] = v;
        }
        __syncthreads();
        unsigned r = run - loc + (wave ? wsum[wave - 1] : 0u);
#pragma unroll
        for (int k = 0; k < 8; ++k) {
            unsigned c = c8[k];
            lh[b0 + k] = r;
            unsigned inc = r + c;
            if (r < KEEP && inc >= KEEP) { shT = (unsigned)(b0 + k); shN = inc; }
            r = inc;
        }
    }
    __syncthreads();
    const unsigned T = shT, ncand = shN;

    // ---- Scatter from LDS scores: pos = lds_base[b] + ticket(cnt)
    if (seg < 15) {
        unsigned* ch = cnt + h * NB;
        ull* Gh = G + (size_t)h * 65536;
        const int t_base = seg * 4096;
        for (int i = tid; i < 4096; i += 1024) {
            float v = s_lds[i];
            int b = bin_of(v, hi, sc);
            if ((unsigned)b <= T) {
                unsigned pos = lh[b] + atomicAdd(&ch[b], 1u);
                ST_A(&Gh[pos], ((ull)desc_key(v) << 16) | (unsigned)(t_base + i));
            }
        }
    }
    arrive(flag, 3); wait_head(flag, 3, h);

    // ---- Phase F: exact rank (static bin bounds from LDS scan); store packed
    {
        ull* csl = (ull*)(smem + 49152);        // 1.5 KB, after lh
        if (tid < NCOMP) csl[tid] = 0ull;
        __syncthreads();
        const ull* Gh = G + (size_t)h * 65536;
        for (unsigned p = seg * 1024 + tid; p < ncand; p += 16384) {
            ull pk = Gh[p];
            unsigned u = (unsigned)(pk >> 16);
            float v = u_to_f(u);
            int b = bin_of(v, hi, sc);
            unsigned start = lh[b];
            unsigned end = (b == NB - 1) ? ncand : lh[b + 1];
            unsigned rank = start;
            for (unsigned j = start; j < end; ++j) rank += (Gh[j] < pk) ? 1u : 0u;
            if (rank < KEEP) {
                ST_A(&stokv[h * KEEP + rank], pk);
                long long f = llrintf(v * 16777216.f);
                atomicAdd(&csl[rank >> 6], (ull)f);
            }
        }
        __syncthreads();
        if (tid < NCOMP) {
            ull c = csl[tid];
            if (c) atomicAdd(&cs_fix[tid], c);
        }
    }
    arrive(flag, 4); wait_all(flag, 4);

    // ---- Phase H: top-32 (redundant/block) + partial softmax+PV (2 pairs/blk)
    {
        ull* key = (ull*)smem;                       // 2048 B
        unsigned* sel_l = (unsigned*)(smem + 2048);  // 128 B
        float* scm = (float*)(smem + 2176);          // 512 B (2x64)
        float* exb = (float*)(smem + 2688);          // 512 B (2x64)
        float* vbuf = (float*)(smem + 3200);         // 2 x 64 x 68 floats
        if (tid < 256) {
            long long v = (long long)cs_fix[tid];    // plain: first touch post-F
            ull bb = (ull)(v + (1ll << 45));
            key[tid] = (((1ull << 46) - bb) << 8) | (unsigned)tid;
        }
        __syncthreads();
        for (unsigned k = 2; k <= 256; k <<= 1) {
            for (unsigned j = k >> 1; j > 0; j >>= 1) {
                if (tid < 256) {
                    unsigned ixj = tid ^ j;
                    if (ixj > (unsigned)tid) {
                        ull a = key[tid], b = key[ixj];
                        bool up = ((tid & k) == 0);
                        if (up ? (a > b) : (a < b)) { key[tid] = b; key[ixj] = a; }
                    }
                }
                __syncthreads();
            }
        }
        if (tid < NSEL) sel_l[tid] = (unsigned)(key[tid] & 0xFFull);
        __syncthreads();

        int su = tid >> 9, sid = tid & 511;
        int p = bid * 2 + su;                    // 0..511; hh == bid>>4 == h
        int hh = p >> 5, ci = p & 31;
        int c = (int)sel_l[ci];
        int g = sid >> 3, q8 = sid & 7;
        int t; float sv;
        if (c < NCOMP) {
            ull pk = stokv[hh * KEEP + c * 64 + g];   // plain: first touch
            t = (int)(pk & 0xFFFFull);
            sv = u_to_f((unsigned)(pk >> 16));
        } else {
            int j = (c - NCOMP) * 64 + g;
            t = PAST + j;
            sv = s_win[hh * 4096 + j];                // plain: first touch
        }
        if (q8 == 0) scm[su * 64 + g] = sv * 0.125f;
        __syncthreads();
        float m = -1e30f;
        for (int j = 0; j < 64; ++j) m = fmaxf(m, scm[su * 64 + j]);
        float e = expf(scm[su * 64 + g] - m);
        if (q8 == 0) exb[su * 64 + g] = e;
        const float4* vrow = (const float4*)(vc + (size_t)t * C + hh * HS);
        float4 v0 = vrow[q8 * 2], v1 = vrow[q8 * 2 + 1];
        float* vb = vbuf + su * 4352 + g * 68 + q8 * 8;
        vb[0] = e * v0.x; vb[1] = e * v0.y; vb[2] = e * v0.z; vb[3] = e * v0.w;
        vb[4] = e * v1.x; vb[5] = e * v1.y; vb[6] = e * v1.z; vb[7] = e * v1.w;
        __syncthreads();
        if (sid < 64) {
            float acc = 0.f;
            for (int g2 = 0; g2 < 64; ++g2) acc += vbuf[su * 4352 + g2 * 68 + sid];
            float* P = part + (size_t)(hh * 32 + ci) * 68;
            ST_A(&P[2 + sid], acc);
            if (sid == 0) {
                float es = 0.f;
                for (int g2 = 0; g2 < 64; ++g2) es += exb[su * 64 + g2];
                ST_A(&P[0], m);
                ST_A(&P[1], es);
            }
        }
    }
    arrive(flag, 5); wait_head(flag, 5, h);

    // ---- Wo prefetch (independent of y) hides under the y barrier
    int row = bid * 4 + (wave >> 2), qtr = wave & 3;
    const float4* Wrow4 = (const float4*)(Wo + (size_t)row * C) + qtr * 64;
    float4 wa = Wrow4[lane];

    // ---- y[h]: combined once per head (seg 0), 64 lanes
    if (seg == 0 && tid < 64) {
        float p = q[h * 64 + tid] * kn[h * 64 + tid];
#pragma unroll
        for (int off = 32; off; off >>= 1) p += __shfl_xor(p, off);
        float a_new = p * 0.125f;
        const float* P0 = part + (size_t)h * 32 * 68;   // plain: head-local
        float m = a_new;
        for (int ci = 0; ci < 32; ++ci) m = fmaxf(m, P0[ci * 68]);
        float den = expf(a_new - m);
        float acc = den * vn[h * HS + tid];
        for (int ci = 0; ci < 32; ++ci) {
            float w = expf(P0[ci * 68] - m);
            den += w * P0[ci * 68 + 1];
            acc += w * P0[ci * 68 + 2 + tid];
        }
        ST_A(&yg[h * HS + tid], acc / den);
    }
    if (seg == 0) arrive(flag, 6);             // only y-writers publish phase 6
    if (tid < 16)
        while (LD_A(&flag[(tid * 16) * FLAGW]) < 6u) __builtin_amdgcn_s_sleep(2);
    __syncthreads();

    // ---- Wo matmul: block bid -> rows [bid*4, bid*4+4), wave = (row, quarter)
    {
        float* yl = (float*)smem;                 // 4 KB
        float* ps = (float*)(smem + 4096);        // 64 B
        yl[tid] = yg[tid];                        // plain: first touch this block
        __syncthreads();
        const float4* y4 = (const float4*)yl + qtr * 64;
        float4 b = y4[lane];
        float acc = wa.x * b.x + wa.y * b.y + wa.z * b.z + wa.w * b.w;
#pragma unroll
        for (int off = 32; off; off >>= 1) acc += __shfl_xor(acc, off);
        if (lane == 0) ps[wave] = acc;
        __syncthreads();
        if (tid < 4)
            out[bid * 4 + tid] = ps[tid * 4] + ps[tid * 4 + 1] + ps[tid * 4 + 2] + ps[tid * 4 + 3];
    }
}

extern "C" void kernel_launch(void* const* d_in, const int* in_sizes, int n_in,
                              void* d_out, int out_size, void* d_ws, size_t ws_size,
                              hipStream_t stream) {
    const float* x  = (const float*)d_in[0];
    const float* kc = (const float*)d_in[1];
    const float* vc = (const float*)d_in[2];
    const float* Wr = (const float*)d_in[3];
    const float* Wk = (const float*)d_in[4];
    const float* Wv = (const float*)d_in[5];
    const float* Wo = (const float*)d_in[6];
    float* out = (float*)d_out;
    char* ws = (char*)d_ws;

    float* q    = (float*)(ws + 0);
    float* kn   = (float*)(ws + 8192);
    float* vn   = (float*)(ws + 16384);
    ull* cs_fix = (ull*)(ws + 32768);                  // 2 KiB
    float* yg   = (float*)(ws + 40960);                // 4 KiB
    float* part = (float*)(ws + 49152);                // 139264 B -> ends 188416
    unsigned* umin = (unsigned*)(ws + 188416);
    unsigned* umax = (unsigned*)(ws + 188480);
    unsigned* flag = (unsigned*)(ws + 192512);         // 8 KiB (256 x 32B)
    float* s_win   = (float*)(ws + 262144);            // 256 KiB -> ends 524288
    ull* stokv     = (ull*)(ws + 524288);              // 1.5 MiB -> ends 2097152
    unsigned* hist = (unsigned*)(ws + 2097152);        // 512 KiB
    unsigned* cnt  = (unsigned*)(ws + 2621440);        // 512 KiB (contiguous after hist)
    ull* G = (ull*)(ws + 3145728);                     // 8 MiB

    k_proj<<<768, 256, 0, stream>>>(x, Wr, Wk, Wv, q, kn, vn, hist, umin, umax, cs_fix, flag);
    k_mega<<<NBLK, 1024, 0, stream>>>(kc, vc, umin, umax, hist, cnt, G, stokv, cs_fix,
                                      part, q, kn, vn, Wo, yg, out, s_win, flag);
}